// Round 1
// 777.855 us; speedup vs baseline: 1.0070x; 1.0070x over previous
//
#include <hip/hip_runtime.h>

// ---------------------------------------------------------------------------
// AttentionRelativeBias: B=128, S=256, D=768, H=12, DH=64, window 8x8 (=64 tok)
// Pipeline: fused QKV GEMM (reg-staged fp32->bf16 A+B, XOR-swizzled LDS)
//           -> V transpose -> attention (DMA-staged tiles) -> out proj GEMM
// ws layout (201.3 MB, unchanged):
//   [qh 50.3MB][kh 50.3MB][vh 50.3MB -> reused as ctx][vt 50.3MB]
//
// Round theory: gemm_qkv was stall-bound (MfmaUtil 12%, 1.2e8 LDS bank-conflict
// cycles ~= 50% of kernel cycles) from fp32-A-in-LDS + stride-128/256B row
// conflicts. Fix: bf16 A staged via regs (LDS 48->32KB, conflict-free XOR
// swizzle on both tiles); gemm_out gets source-swizzled DMA + swizzled reads.
// ---------------------------------------------------------------------------

typedef __bf16 bf16;
typedef __bf16 bf16x8 __attribute__((ext_vector_type(8)));
typedef float  f32x4  __attribute__((ext_vector_type(4)));

#define MFMA_BF16(a, b, c) __builtin_amdgcn_mfma_f32_16x16x32_bf16((a), (b), (c), 0, 0, 0)

__device__ __forceinline__ void gld16(const void* g, void* l) {
    __builtin_amdgcn_global_load_lds(
        (const __attribute__((address_space(1))) void*)g,
        (__attribute__((address_space(3))) void*)l, 16, 0, 0);
}

__device__ __forceinline__ bf16x8 pack8(f32x4 lo, f32x4 hi) {
    bf16x8 r;
    r[0] = (bf16)lo[0]; r[1] = (bf16)lo[1]; r[2] = (bf16)lo[2]; r[3] = (bf16)lo[3];
    r[4] = (bf16)hi[0]; r[5] = (bf16)hi[1]; r[6] = (bf16)hi[2]; r[7] = (bf16)hi[3];
    return r;
}

// LDS tile: [128 rows][64 bf16] = rows of 8 x 16B granules.
// Swizzle: granule g of row r lives at slot g ^ (r & 7).  Bank of a slot is
// 4*slot % 32, independent of row (row stride 128B == 0 mod 32 dwords), so
// the XOR spreads the 16-lane fragment-read groups across all banks:
// ds_read_b128 / ds_write_b128 both land at exactly 8 lanes/bank (= minimum).
__device__ __forceinline__ int swz8(int row, int g) { return g ^ (row & 7); }

// ---------------- fused QKV projection GEMM -------------------------------
// Y = X @ W^T + b ; X fp32 [32768,768], W fp32 [768,768]; out bf16 [B,H,S,DH]
__global__ __launch_bounds__(256)
void gemm_qkv(const float* __restrict__ q, const float* __restrict__ k,
              const float* __restrict__ v,
              const float* __restrict__ Wq, const float* __restrict__ Wk,
              const float* __restrict__ Wv,
              const float* __restrict__ bq, const float* __restrict__ bk,
              const float* __restrict__ bv, bf16* __restrict__ outbase)
{
    __shared__ bf16 As[128 * 64];   // 16 KB, swizzled
    __shared__ bf16 Bs[128 * 64];   // 16 KB, swizzled
    // total 32 KB -> up to 5 blocks/CU (was 48 KB -> 3)

    const int z = blockIdx.z;
    const float* X    = (z == 0) ? q  : (z == 1) ? k  : v;
    const float* Wt   = (z == 0) ? Wq : (z == 1) ? Wk : Wv;
    const float* bias = (z == 0) ? bq : (z == 1) ? bk : bv;
    bf16* out = outbase + (size_t)z * 25165824;

    const int tid  = threadIdx.x;
    const int m0   = blockIdx.x * 128;
    const int n0   = blockIdx.y * 128;
    const int w    = tid >> 6;
    const int lane = tid & 63;
    const int quad = lane >> 4;
    const int l15  = lane & 15;
    const int wr   = (w >> 1) * 64;
    const int wc   = (w & 1) * 64;

    f32x4 acc[4][4] = {};

    for (int kt = 0; kt < 12; ++kt) {
        const int k0 = kt * 64;
        __syncthreads();
        // A tile 128x64: fp32 -> bf16 at stage time, swizzled ds_write_b128.
        // g = granule-pair index; per instr: 8 rows x full 256B -> coalesced.
        #pragma unroll
        for (int p = 0; p < 4; ++p) {
            int g = p * 256 + tid;
            int row = g >> 3, gp = g & 7;
            const float* src = X + (size_t)(m0 + row) * 768 + k0 + gp * 8;
            *(bf16x8*)&As[row * 64 + swz8(row, gp) * 8] =
                pack8(*(const f32x4*)src, *(const f32x4*)(src + 4));
        }
        // B tile 128x64 -> bf16, swizzled (weights tiny, L2-resident)
        #pragma unroll
        for (int p = 0; p < 4; ++p) {
            int g = p * 256 + tid;
            int row = g >> 3, gp = g & 7;
            const float* src = Wt + (size_t)(n0 + row) * 768 + k0 + gp * 8;
            *(bf16x8*)&Bs[row * 64 + swz8(row, gp) * 8] =
                pack8(*(const f32x4*)src, *(const f32x4*)(src + 4));
        }
        __syncthreads();
        #pragma unroll
        for (int kk = 0; kk < 2; ++kk) {
            bf16x8 af[4], bfr[4];
            #pragma unroll
            for (int mt = 0; mt < 4; ++mt) {
                int row = wr + mt * 16 + l15;
                af[mt] = *(const bf16x8*)&As[row * 64 + swz8(row, kk * 4 + quad) * 8];
            }
            #pragma unroll
            for (int nt = 0; nt < 4; ++nt) {
                int row = wc + nt * 16 + l15;
                bfr[nt] = *(const bf16x8*)&Bs[row * 64 + swz8(row, kk * 4 + quad) * 8];
            }
            #pragma unroll
            for (int mt = 0; mt < 4; ++mt)
                #pragma unroll
                for (int nt = 0; nt < 4; ++nt)
                    acc[mt][nt] = MFMA_BF16(af[mt], bfr[nt], acc[mt][nt]);
        }
    }

    #pragma unroll
    for (int mt = 0; mt < 4; ++mt) {
        #pragma unroll
        for (int nt = 0; nt < 4; ++nt) {
            int gn = n0 + wc + nt * 16 + l15;
            float bv = bias[gn];
            int h = gn >> 6, d = gn & 63;
            #pragma unroll
            for (int r = 0; r < 4; ++r) {
                int gm = m0 + wr + mt * 16 + quad * 4 + r;
                int b = gm >> 8, s = gm & 255;
                out[(((size_t)(b * 12 + h) << 8) + s) * 64 + d] = (bf16)(acc[mt][nt][r] + bv);
            }
        }
    }
}

// ---------------- output projection GEMM ----------------------------------
// out fp32 [32768,768] = ctx(bf16) @ Wo^T + bo
// A tile DMA'd (global_load_lds, linear dest) with INVERSE-swizzled global
// source, so LDS slot g of row r holds source granule g^(r&7); reads apply
// the same XOR (rule-21: both-sides-or-neither).
__global__ __launch_bounds__(256)
void gemm_out(const bf16* __restrict__ X, const float* __restrict__ Wt,
              const float* __restrict__ bias, float* __restrict__ out)
{
    __shared__ bf16 As[128 * 64];
    __shared__ bf16 Bs[128 * 64];

    const int tid  = threadIdx.x;
    const int m0   = blockIdx.x * 128;
    const int n0   = blockIdx.y * 128;
    const int w    = tid >> 6;
    const int lane = tid & 63;
    const int quad = lane >> 4;
    const int l15  = lane & 15;
    const int wr   = (w >> 1) * 64;
    const int wc   = (w & 1) * 64;

    f32x4 acc[4][4] = {};

    for (int kt = 0; kt < 12; ++kt) {
        const int k0 = kt * 64;
        __syncthreads();
        #pragma unroll
        for (int p = 0; p < 4; ++p) {
            int g = p * 256 + tid;
            int row = g >> 3;
            int cg  = swz8(row, g & 7);   // pre-swizzled source column granule
            gld16(X + (size_t)(m0 + row) * 768 + k0 + cg * 8,
                  (char*)As + g * 16);
        }
        #pragma unroll
        for (int p = 0; p < 4; ++p) {
            int g = p * 256 + tid;
            int row = g >> 3, gp = g & 7;
            const float* src = Wt + (size_t)(n0 + row) * 768 + k0 + gp * 8;
            *(bf16x8*)&Bs[row * 64 + swz8(row, gp) * 8] =
                pack8(*(const f32x4*)src, *(const f32x4*)(src + 4));
        }
        __syncthreads();
        #pragma unroll
        for (int kk = 0; kk < 2; ++kk) {
            bf16x8 af[4], bfr[4];
            #pragma unroll
            for (int mt = 0; mt < 4; ++mt) {
                int row = wr + mt * 16 + l15;
                af[mt] = *(const bf16x8*)&As[row * 64 + swz8(row, kk * 4 + quad) * 8];
            }
            #pragma unroll
            for (int nt = 0; nt < 4; ++nt) {
                int row = wc + nt * 16 + l15;
                bfr[nt] = *(const bf16x8*)&Bs[row * 64 + swz8(row, kk * 4 + quad) * 8];
            }
            #pragma unroll
            for (int mt = 0; mt < 4; ++mt)
                #pragma unroll
                for (int nt = 0; nt < 4; ++nt)
                    acc[mt][nt] = MFMA_BF16(af[mt], bfr[nt], acc[mt][nt]);
        }
    }

    #pragma unroll
    for (int mt = 0; mt < 4; ++mt) {
        #pragma unroll
        for (int nt = 0; nt < 4; ++nt) {
            int gn = n0 + wc + nt * 16 + l15;
            float bv = bias[gn];
            #pragma unroll
            for (int r = 0; r < 4; ++r) {
                int gm = m0 + wr + mt * 16 + quad * 4 + r;
                out[(size_t)gm * 768 + gn] = acc[mt][nt][r] + bv;
            }
        }
    }
}

// ---------------- V transpose: [B,H,S,DH] -> [B,H,DH,S] -------------------
// LD=65 (odd) => both scalar LDS directions are <=2-way (free) conflicts.
__global__ __launch_bounds__(256)
void transpose_v(const bf16* __restrict__ vh, bf16* __restrict__ vt)
{
    __shared__ bf16 Ts[64 * 65];
    const int qt = blockIdx.x, h = blockIdx.y, b = blockIdx.z;
    const bf16* src = vh + ((size_t)(b * 12 + h) * 256 + qt * 64) * 64;
    bf16* dst = vt + (size_t)(b * 12 + h) * 64 * 256;

    const int tid = threadIdx.x;
    {
        int row = tid >> 2, c0 = (tid & 3) * 16;
        bf16x8 v0 = *(const bf16x8*)(src + row * 64 + c0);
        bf16x8 v1 = *(const bf16x8*)(src + row * 64 + c0 + 8);
        #pragma unroll
        for (int i = 0; i < 8; ++i) {
            Ts[row * 65 + c0 + i]     = v0[i];
            Ts[row * 65 + c0 + 8 + i] = v1[i];
        }
    }
    __syncthreads();
    {
        int d = tid >> 2, j0 = (tid & 3) * 16;
        bf16x8 o0, o1;
        #pragma unroll
        for (int i = 0; i < 8; ++i) {
            o0[i] = Ts[(j0 + i) * 65 + d];
            o1[i] = Ts[(j0 + 8 + i) * 65 + d];
        }
        *(bf16x8*)(dst + (size_t)d * 256 + qt * 64 + j0)     = o0;
        *(bf16x8*)(dst + (size_t)d * 256 + qt * 64 + j0 + 8) = o1;
    }
}

// ---------------- attention ------------------------------------------------
__global__ __launch_bounds__(256)
void attn_kernel(const bf16* __restrict__ qh, const bf16* __restrict__ kh,
                 const bf16* __restrict__ vt, const float* __restrict__ table,
                 bf16* __restrict__ ctx)
{
    __shared__ bf16 Qs[64 * 64];       // 8 KB, DMA-staged, unpadded
    __shared__ bf16 Ks[64 * 64];       // 8 KB
    __shared__ bf16 Vs[64 * 64];       // 8 KB (V^T chunk: [d][j_local])
    __shared__ bf16 Ps[4 * 16 * 72];   // 9.2 KB (per-wave P, LD=72)
    __shared__ bf16 Bsh[64 * 68];      // 8.7 KB bias tile
    // total 42.5 KB -> 3 blocks/CU

    const int tid  = threadIdx.x;
    const int qt   = blockIdx.x;
    const int h    = blockIdx.y;
    const int b    = blockIdx.z;
    const int w    = tid >> 6;
    const int lane = tid & 63;
    const int quad = lane >> 4;
    const int l15  = lane & 15;

    const size_t bh = (size_t)(b * 12 + h) * 256 * 64;
    const bf16* Qg  = qh + bh + (size_t)qt * 64 * 64;
    const bf16* Kg  = kh + bh;
    const bf16* Vtg = vt + bh;   // [64][256]

    // stage Q (DMA) + build bias tile
    #pragma unroll
    for (int p = 0; p < 2; ++p) {
        int g = p * 256 + tid;
        gld16(Qg + (size_t)(g >> 3) * 64 + (g & 7) * 8, (char*)Qs + g * 16);
    }
    {
        int i = tid >> 2, j0 = (tid & 3) * 16;
        int ai = i >> 3, aj = i & 7;
        #pragma unroll
        for (int jj = 0; jj < 16; ++jj) {
            int j = j0 + jj;
            int idx = (ai - (j >> 3) + 7) * 15 + (aj - (j & 7) + 7);
            Bsh[i * 68 + j] = (bf16)table[idx * 12 + h];
        }
    }

    // ---- QK^T over 4 key chunks ----
    f32x4 sacc[16] = {};
    bf16x8 qf0, qf1;
    for (int c = 0; c < 4; ++c) {
        __syncthreads();
        #pragma unroll
        for (int p = 0; p < 2; ++p) {
            int g = p * 256 + tid;
            gld16(Kg + (size_t)(c * 64 + (g >> 3)) * 64 + (g & 7) * 8, (char*)Ks + g * 16);
        }
        __syncthreads();
        if (c == 0) {
            qf0 = *(const bf16x8*)&Qs[(w * 16 + l15) * 64 + quad * 8];
            qf1 = *(const bf16x8*)&Qs[(w * 16 + l15) * 64 + 32 + quad * 8];
        }
        #pragma unroll
        for (int jtl = 0; jtl < 4; ++jtl) {
            bf16x8 kf0 = *(const bf16x8*)&Ks[(jtl * 16 + l15) * 64 + quad * 8];
            bf16x8 kf1 = *(const bf16x8*)&Ks[(jtl * 16 + l15) * 64 + 32 + quad * 8];
            sacc[c * 4 + jtl] = MFMA_BF16(qf0, kf0, sacc[c * 4 + jtl]);
            sacc[c * 4 + jtl] = MFMA_BF16(qf1, kf1, sacc[c * 4 + jtl]);
        }
    }

    // ---- softmax ----
    const int browbase = w * 16 + quad * 4;
    float p[16][4];
    #pragma unroll
    for (int jt = 0; jt < 16; ++jt) {
        int jcol = ((jt * 16) & 63) + l15;
        #pragma unroll
        for (int r = 0; r < 4; ++r)
            p[jt][r] = sacc[jt][r] * 0.125f + (float)Bsh[(browbase + r) * 68 + jcol];
    }
    float invl[4];
    #pragma unroll
    for (int r = 0; r < 4; ++r) {
        float m = p[0][r];
        #pragma unroll
        for (int jt = 1; jt < 16; ++jt) m = fmaxf(m, p[jt][r]);
        #pragma unroll
        for (int off = 1; off < 16; off <<= 1)
            m = fmaxf(m, __shfl_xor(m, off, 64));
        float s = 0.f;
        #pragma unroll
        for (int jt = 0; jt < 16; ++jt) {
            p[jt][r] = __expf(p[jt][r] - m);
            s += p[jt][r];
        }
        #pragma unroll
        for (int off = 1; off < 16; off <<= 1)
            s += __shfl_xor(s, off, 64);
        invl[r] = 1.0f / s;
    }

    // ---- PV over 4 key chunks ----
    f32x4 cacc[4] = {};
    bf16* Pw = &Ps[w * 16 * 72];
    for (int c = 0; c < 4; ++c) {
        __syncthreads();
        #pragma unroll
        for (int pp = 0; pp < 2; ++pp) {
            int g = pp * 256 + tid;   // row = d, col chunk within [c*64, c*64+64)
            gld16(Vtg + (size_t)(g >> 3) * 256 + c * 64 + (g & 7) * 8, (char*)Vs + g * 16);
        }
        #pragma unroll
        for (int jtl = 0; jtl < 4; ++jtl) {
            int jt = c * 4 + jtl;
            #pragma unroll
            for (int r = 0; r < 4; ++r)
                Pw[(quad * 4 + r) * 72 + jtl * 16 + l15] = (bf16)(p[jt][r] * invl[r]);
        }
        __syncthreads();
        bf16x8 pf0 = *(const bf16x8*)&Pw[l15 * 72 + quad * 8];
        bf16x8 pf1 = *(const bf16x8*)&Pw[l15 * 72 + 32 + quad * 8];
        #pragma unroll
        for (int dt = 0; dt < 4; ++dt) {
            bf16x8 vf0 = *(const bf16x8*)&Vs[(dt * 16 + l15) * 64 + quad * 8];
            bf16x8 vf1 = *(const bf16x8*)&Vs[(dt * 16 + l15) * 64 + 32 + quad * 8];
            cacc[dt] = MFMA_BF16(pf0, vf0, cacc[dt]);
            cacc[dt] = MFMA_BF16(pf1, vf1, cacc[dt]);
        }
    }

    // ---- store ctx [B, S, 768] bf16 ----
    const size_t obase = ((size_t)b * 256) * 768 + (size_t)h * 64;
    #pragma unroll
    for (int dt = 0; dt < 4; ++dt) {
        #pragma unroll
        for (int r = 0; r < 4; ++r) {
            int s = qt * 64 + w * 16 + quad * 4 + r;
            int d = dt * 16 + l15;
            ctx[obase + (size_t)s * 768 + d] = (bf16)cacc[dt][r];
        }
    }
}

extern "C" void kernel_launch(void* const* d_in, const int* in_sizes, int n_in,
                              void* d_out, int out_size, void* d_ws, size_t ws_size,
                              hipStream_t stream) {
    (void)in_sizes; (void)n_in; (void)out_size; (void)ws_size;
    const float* q     = (const float*)d_in[0];
    const float* k     = (const float*)d_in[1];
    const float* v     = (const float*)d_in[2];
    const float* Wq    = (const float*)d_in[3];
    const float* bq    = (const float*)d_in[4];
    const float* Wk    = (const float*)d_in[5];
    const float* bk    = (const float*)d_in[6];
    const float* Wv    = (const float*)d_in[7];
    const float* bv    = (const float*)d_in[8];
    const float* Wo    = (const float*)d_in[9];
    const float* bo    = (const float*)d_in[10];
    const float* table = (const float*)d_in[11];

    const size_t NE = (size_t)128 * 256 * 768;
    bf16* qh  = (bf16*)d_ws;
    bf16* kh  = qh + NE;
    bf16* vh  = kh + NE;        // reused as ctx after transpose_v consumes it
    bf16* vt  = vh + NE;
    bf16* ctx = vh;
    float* out = (float*)d_out;

    dim3 blk(256);
    gemm_qkv<<<dim3(256, 6, 3), blk, 0, stream>>>(q, k, v, Wq, Wk, Wv, bq, bk, bv, qh);
    transpose_v<<<dim3(4, 12, 128), blk, 0, stream>>>(vh, vt);
    attn_kernel<<<dim3(4, 12, 128), blk, 0, stream>>>(qh, kh, vt, table, ctx);
    gemm_out<<<dim3(256, 6), blk, 0, stream>>>(ctx, Wo, bo, out);
}

// Round 2
// 739.187 us; speedup vs baseline: 1.0597x; 1.0523x over previous
//
#include <hip/hip_runtime.h>

// ---------------------------------------------------------------------------
// AttentionRelativeBias: B=128, S=256, D=768, H=12, DH=64, window 8x8 (=64 tok)
// Pipeline: fused QKV GEMM -> V transpose -> attention -> out proj GEMM
// ws layout (201.3 MB, unchanged):
//   [qh 50.3MB][kh 50.3MB][vh 50.3MB -> reused as ctx][vt 50.3MB]
//
// Round 2 theory: R1 killed bank conflicts (1.2e8 -> 0) with NO time change ->
// 2-barrier serial staging is the critical path (all pipes <25% busy, pure
// latency). Fix: double-buffered LDS + reg-staged prefetch. Per K-step:
// issue t+1 global loads -> compute t from LDS -> pack/ds_write t+1 (vmcnt
// waits here, latency hidden under MFMA) -> ONE barrier. Applied to both
// GEMMs; attn/transpose unchanged.
// ---------------------------------------------------------------------------

typedef __bf16 bf16;
typedef __bf16 bf16x8 __attribute__((ext_vector_type(8)));
typedef float  f32x4  __attribute__((ext_vector_type(4)));

#define MFMA_BF16(a, b, c) __builtin_amdgcn_mfma_f32_16x16x32_bf16((a), (b), (c), 0, 0, 0)

__device__ __forceinline__ void gld16(const void* g, void* l) {
    __builtin_amdgcn_global_load_lds(
        (const __attribute__((address_space(1))) void*)g,
        (__attribute__((address_space(3))) void*)l, 16, 0, 0);
}

__device__ __forceinline__ bf16x8 pack8(f32x4 lo, f32x4 hi) {
    bf16x8 r;
    r[0] = (bf16)lo[0]; r[1] = (bf16)lo[1]; r[2] = (bf16)lo[2]; r[3] = (bf16)lo[3];
    r[4] = (bf16)hi[0]; r[5] = (bf16)hi[1]; r[6] = (bf16)hi[2]; r[7] = (bf16)hi[3];
    return r;
}

// LDS tile: [128 rows][64 bf16] = rows of 8 x 16B granules, granule g of row r
// lives at slot g ^ (r&7)  => ds_read_b128 / ds_write_b128 conflict-free.
__device__ __forceinline__ int swz8(int row, int g) { return g ^ (row & 7); }

// ---------------- fused QKV projection GEMM -------------------------------
// Y = X @ W^T + b ; X fp32 [32768,768], W fp32 [768,768]; out bf16 [B,H,S,DH]
__global__ __launch_bounds__(256)
void gemm_qkv(const float* __restrict__ q, const float* __restrict__ k,
              const float* __restrict__ v,
              const float* __restrict__ Wq, const float* __restrict__ Wk,
              const float* __restrict__ Wv,
              const float* __restrict__ bq, const float* __restrict__ bk,
              const float* __restrict__ bv, bf16* __restrict__ outbase)
{
    __shared__ bf16 As[2][128 * 64];   // 32 KB double-buffered, swizzled
    __shared__ bf16 Bs[2][128 * 64];   // 32 KB
    // total 64 KB -> 2 blocks/CU; latency hidden by ILP (prefetch), not TLP

    const int z = blockIdx.z;
    const float* X    = (z == 0) ? q  : (z == 1) ? k  : v;
    const float* Wt   = (z == 0) ? Wq : (z == 1) ? Wk : Wv;
    const float* bias = (z == 0) ? bq : (z == 1) ? bk : bv;
    bf16* out = outbase + (size_t)z * 25165824;

    const int tid  = threadIdx.x;
    const int m0   = blockIdx.x * 128;
    const int n0   = blockIdx.y * 128;
    const int w    = tid >> 6;
    const int lane = tid & 63;
    const int quad = lane >> 4;
    const int l15  = lane & 15;
    const int wr   = (w >> 1) * 64;
    const int wc   = (w & 1) * 64;

    // per-thread staging coords: 4 granule-pairs (32B) each for A and B
    int srow[4], sgp[4], sdst[4];
    #pragma unroll
    for (int p = 0; p < 4; ++p) {
        int g = p * 256 + tid;
        srow[p] = g >> 3;
        sgp[p]  = g & 7;
        sdst[p] = srow[p] * 64 + swz8(srow[p], sgp[p]) * 8;
    }

    f32x4 acc[4][4] = {};
    f32x4 aL[4], aH[4], bL[4], bH[4];   // in-flight stage registers

    auto load_stage = [&](int k0) {
        #pragma unroll
        for (int p = 0; p < 4; ++p) {
            const float* sa = X + (size_t)(m0 + srow[p]) * 768 + k0 + sgp[p] * 8;
            aL[p] = *(const f32x4*)sa;
            aH[p] = *(const f32x4*)(sa + 4);
            const float* sb = Wt + (size_t)(n0 + srow[p]) * 768 + k0 + sgp[p] * 8;
            bL[p] = *(const f32x4*)sb;
            bH[p] = *(const f32x4*)(sb + 4);
        }
    };
    auto write_stage = [&](int buf) {
        #pragma unroll
        for (int p = 0; p < 4; ++p) {
            *(bf16x8*)&As[buf][sdst[p]] = pack8(aL[p], aH[p]);
            *(bf16x8*)&Bs[buf][sdst[p]] = pack8(bL[p], bH[p]);
        }
    };
    auto compute = [&](int buf) {
        #pragma unroll
        for (int kk = 0; kk < 2; ++kk) {
            bf16x8 af[4], bfr[4];
            #pragma unroll
            for (int mt = 0; mt < 4; ++mt) {
                int row = wr + mt * 16 + l15;
                af[mt] = *(const bf16x8*)&As[buf][row * 64 + swz8(row, kk * 4 + quad) * 8];
            }
            #pragma unroll
            for (int nt = 0; nt < 4; ++nt) {
                int row = wc + nt * 16 + l15;
                bfr[nt] = *(const bf16x8*)&Bs[buf][row * 64 + swz8(row, kk * 4 + quad) * 8];
            }
            #pragma unroll
            for (int mt = 0; mt < 4; ++mt)
                #pragma unroll
                for (int nt = 0; nt < 4; ++nt)
                    acc[mt][nt] = MFMA_BF16(af[mt], bfr[nt], acc[mt][nt]);
        }
    };

    // prologue: stage tile 0
    load_stage(0);
    write_stage(0);
    __syncthreads();

    int cur = 0;
    for (int kt = 0; kt < 11; ++kt) {
        load_stage((kt + 1) * 64);   // issue next-tile loads (fly under MFMA)
        compute(cur);                // ds_read + 32 MFMA on current tile
        write_stage(cur ^ 1);        // vmcnt waits land here, post-compute
        __syncthreads();             // one barrier per K-step
        cur ^= 1;
    }
    compute(cur);                    // last tile, no prefetch

    #pragma unroll
    for (int mt = 0; mt < 4; ++mt) {
        #pragma unroll
        for (int nt = 0; nt < 4; ++nt) {
            int gn = n0 + wc + nt * 16 + l15;
            float bv = bias[gn];
            int h = gn >> 6, d = gn & 63;
            #pragma unroll
            for (int r = 0; r < 4; ++r) {
                int gm = m0 + wr + mt * 16 + quad * 4 + r;
                int b = gm >> 8, s = gm & 255;
                out[(((size_t)(b * 12 + h) << 8) + s) * 64 + d] = (bf16)(acc[mt][nt][r] + bv);
            }
        }
    }
}

// ---------------- output projection GEMM ----------------------------------
// out fp32 [32768,768] = ctx(bf16) @ Wo^T + bo  — same dbuf/prefetch structure
__global__ __launch_bounds__(256)
void gemm_out(const bf16* __restrict__ X, const float* __restrict__ Wt,
              const float* __restrict__ bias, float* __restrict__ out)
{
    __shared__ bf16 As[2][128 * 64];
    __shared__ bf16 Bs[2][128 * 64];

    const int tid  = threadIdx.x;
    const int m0   = blockIdx.x * 128;
    const int n0   = blockIdx.y * 128;
    const int w    = tid >> 6;
    const int lane = tid & 63;
    const int quad = lane >> 4;
    const int l15  = lane & 15;
    const int wr   = (w >> 1) * 64;
    const int wc   = (w & 1) * 64;

    int srow[4], sgp[4], sdst[4];
    #pragma unroll
    for (int p = 0; p < 4; ++p) {
        int g = p * 256 + tid;
        srow[p] = g >> 3;
        sgp[p]  = g & 7;
        sdst[p] = srow[p] * 64 + swz8(srow[p], sgp[p]) * 8;
    }

    f32x4 acc[4][4] = {};
    bf16x8 aR[4];
    f32x4 bL[4], bH[4];

    auto load_stage = [&](int k0) {
        #pragma unroll
        for (int p = 0; p < 4; ++p) {
            aR[p] = *(const bf16x8*)(X + (size_t)(m0 + srow[p]) * 768 + k0 + sgp[p] * 8);
            const float* sb = Wt + (size_t)(n0 + srow[p]) * 768 + k0 + sgp[p] * 8;
            bL[p] = *(const f32x4*)sb;
            bH[p] = *(const f32x4*)(sb + 4);
        }
    };
    auto write_stage = [&](int buf) {
        #pragma unroll
        for (int p = 0; p < 4; ++p) {
            *(bf16x8*)&As[buf][sdst[p]] = aR[p];
            *(bf16x8*)&Bs[buf][sdst[p]] = pack8(bL[p], bH[p]);
        }
    };
    auto compute = [&](int buf) {
        #pragma unroll
        for (int kk = 0; kk < 2; ++kk) {
            bf16x8 af[4], bfr[4];
            #pragma unroll
            for (int mt = 0; mt < 4; ++mt) {
                int row = wr + mt * 16 + l15;
                af[mt] = *(const bf16x8*)&As[buf][row * 64 + swz8(row, kk * 4 + quad) * 8];
            }
            #pragma unroll
            for (int nt = 0; nt < 4; ++nt) {
                int row = wc + nt * 16 + l15;
                bfr[nt] = *(const bf16x8*)&Bs[buf][row * 64 + swz8(row, kk * 4 + quad) * 8];
            }
            #pragma unroll
            for (int mt = 0; mt < 4; ++mt)
                #pragma unroll
                for (int nt = 0; nt < 4; ++nt)
                    acc[mt][nt] = MFMA_BF16(af[mt], bfr[nt], acc[mt][nt]);
        }
    };

    load_stage(0);
    write_stage(0);
    __syncthreads();

    int cur = 0;
    for (int kt = 0; kt < 11; ++kt) {
        load_stage((kt + 1) * 64);
        compute(cur);
        write_stage(cur ^ 1);
        __syncthreads();
        cur ^= 1;
    }
    compute(cur);

    #pragma unroll
    for (int mt = 0; mt < 4; ++mt) {
        #pragma unroll
        for (int nt = 0; nt < 4; ++nt) {
            int gn = n0 + wc + nt * 16 + l15;
            float bv = bias[gn];
            #pragma unroll
            for (int r = 0; r < 4; ++r) {
                int gm = m0 + wr + mt * 16 + quad * 4 + r;
                out[(size_t)gm * 768 + gn] = acc[mt][nt][r] + bv;
            }
        }
    }
}

// ---------------- V transpose: [B,H,S,DH] -> [B,H,DH,S] -------------------
// LD=65 (odd) => both scalar LDS directions are <=2-way (free) conflicts.
__global__ __launch_bounds__(256)
void transpose_v(const bf16* __restrict__ vh, bf16* __restrict__ vt)
{
    __shared__ bf16 Ts[64 * 65];
    const int qt = blockIdx.x, h = blockIdx.y, b = blockIdx.z;
    const bf16* src = vh + ((size_t)(b * 12 + h) * 256 + qt * 64) * 64;
    bf16* dst = vt + (size_t)(b * 12 + h) * 64 * 256;

    const int tid = threadIdx.x;
    {
        int row = tid >> 2, c0 = (tid & 3) * 16;
        bf16x8 v0 = *(const bf16x8*)(src + row * 64 + c0);
        bf16x8 v1 = *(const bf16x8*)(src + row * 64 + c0 + 8);
        #pragma unroll
        for (int i = 0; i < 8; ++i) {
            Ts[row * 65 + c0 + i]     = v0[i];
            Ts[row * 65 + c0 + 8 + i] = v1[i];
        }
    }
    __syncthreads();
    {
        int d = tid >> 2, j0 = (tid & 3) * 16;
        bf16x8 o0, o1;
        #pragma unroll
        for (int i = 0; i < 8; ++i) {
            o0[i] = Ts[(j0 + i) * 65 + d];
            o1[i] = Ts[(j0 + 8 + i) * 65 + d];
        }
        *(bf16x8*)(dst + (size_t)d * 256 + qt * 64 + j0)     = o0;
        *(bf16x8*)(dst + (size_t)d * 256 + qt * 64 + j0 + 8) = o1;
    }
}

// ---------------- attention ------------------------------------------------
__global__ __launch_bounds__(256)
void attn_kernel(const bf16* __restrict__ qh, const bf16* __restrict__ kh,
                 const bf16* __restrict__ vt, const float* __restrict__ table,
                 bf16* __restrict__ ctx)
{
    __shared__ bf16 Qs[64 * 64];       // 8 KB, DMA-staged, unpadded
    __shared__ bf16 Ks[64 * 64];       // 8 KB
    __shared__ bf16 Vs[64 * 64];       // 8 KB (V^T chunk: [d][j_local])
    __shared__ bf16 Ps[4 * 16 * 72];   // 9.2 KB (per-wave P, LD=72)
    __shared__ bf16 Bsh[64 * 68];      // 8.7 KB bias tile
    // total 42.5 KB -> 3 blocks/CU

    const int tid  = threadIdx.x;
    const int qt   = blockIdx.x;
    const int h    = blockIdx.y;
    const int b    = blockIdx.z;
    const int w    = tid >> 6;
    const int lane = tid & 63;
    const int quad = lane >> 4;
    const int l15  = lane & 15;

    const size_t bh = (size_t)(b * 12 + h) * 256 * 64;
    const bf16* Qg  = qh + bh + (size_t)qt * 64 * 64;
    const bf16* Kg  = kh + bh;
    const bf16* Vtg = vt + bh;   // [64][256]

    // stage Q (DMA) + build bias tile
    #pragma unroll
    for (int p = 0; p < 2; ++p) {
        int g = p * 256 + tid;
        gld16(Qg + (size_t)(g >> 3) * 64 + (g & 7) * 8, (char*)Qs + g * 16);
    }
    {
        int i = tid >> 2, j0 = (tid & 3) * 16;
        int ai = i >> 3, aj = i & 7;
        #pragma unroll
        for (int jj = 0; jj < 16; ++jj) {
            int j = j0 + jj;
            int idx = (ai - (j >> 3) + 7) * 15 + (aj - (j & 7) + 7);
            Bsh[i * 68 + j] = (bf16)table[idx * 12 + h];
        }
    }

    // ---- QK^T over 4 key chunks ----
    f32x4 sacc[16] = {};
    bf16x8 qf0, qf1;
    for (int c = 0; c < 4; ++c) {
        __syncthreads();
        #pragma unroll
        for (int p = 0; p < 2; ++p) {
            int g = p * 256 + tid;
            gld16(Kg + (size_t)(c * 64 + (g >> 3)) * 64 + (g & 7) * 8, (char*)Ks + g * 16);
        }
        __syncthreads();
        if (c == 0) {
            qf0 = *(const bf16x8*)&Qs[(w * 16 + l15) * 64 + quad * 8];
            qf1 = *(const bf16x8*)&Qs[(w * 16 + l15) * 64 + 32 + quad * 8];
        }
        #pragma unroll
        for (int jtl = 0; jtl < 4; ++jtl) {
            bf16x8 kf0 = *(const bf16x8*)&Ks[(jtl * 16 + l15) * 64 + quad * 8];
            bf16x8 kf1 = *(const bf16x8*)&Ks[(jtl * 16 + l15) * 64 + 32 + quad * 8];
            sacc[c * 4 + jtl] = MFMA_BF16(qf0, kf0, sacc[c * 4 + jtl]);
            sacc[c * 4 + jtl] = MFMA_BF16(qf1, kf1, sacc[c * 4 + jtl]);
        }
    }

    // ---- softmax ----
    const int browbase = w * 16 + quad * 4;
    float p[16][4];
    #pragma unroll
    for (int jt = 0; jt < 16; ++jt) {
        int jcol = ((jt * 16) & 63) + l15;
        #pragma unroll
        for (int r = 0; r < 4; ++r)
            p[jt][r] = sacc[jt][r] * 0.125f + (float)Bsh[(browbase + r) * 68 + jcol];
    }
    float invl[4];
    #pragma unroll
    for (int r = 0; r < 4; ++r) {
        float m = p[0][r];
        #pragma unroll
        for (int jt = 1; jt < 16; ++jt) m = fmaxf(m, p[jt][r]);
        #pragma unroll
        for (int off = 1; off < 16; off <<= 1)
            m = fmaxf(m, __shfl_xor(m, off, 64));
        float s = 0.f;
        #pragma unroll
        for (int jt = 0; jt < 16; ++jt) {
            p[jt][r] = __expf(p[jt][r] - m);
            s += p[jt][r];
        }
        #pragma unroll
        for (int off = 1; off < 16; off <<= 1)
            s += __shfl_xor(s, off, 64);
        invl[r] = 1.0f / s;
    }

    // ---- PV over 4 key chunks ----
    f32x4 cacc[4] = {};
    bf16* Pw = &Ps[w * 16 * 72];
    for (int c = 0; c < 4; ++c) {
        __syncthreads();
        #pragma unroll
        for (int pp = 0; pp < 2; ++pp) {
            int g = pp * 256 + tid;   // row = d, col chunk within [c*64, c*64+64)
            gld16(Vtg + (size_t)(g >> 3) * 256 + c * 64 + (g & 7) * 8, (char*)Vs + g * 16);
        }
        #pragma unroll
        for (int jtl = 0; jtl < 4; ++jtl) {
            int jt = c * 4 + jtl;
            #pragma unroll
            for (int r = 0; r < 4; ++r)
                Pw[(quad * 4 + r) * 72 + jtl * 16 + l15] = (bf16)(p[jt][r] * invl[r]);
        }
        __syncthreads();
        bf16x8 pf0 = *(const bf16x8*)&Pw[l15 * 72 + quad * 8];
        bf16x8 pf1 = *(const bf16x8*)&Pw[l15 * 72 + 32 + quad * 8];
        #pragma unroll
        for (int dt = 0; dt < 4; ++dt) {
            bf16x8 vf0 = *(const bf16x8*)&Vs[(dt * 16 + l15) * 64 + quad * 8];
            bf16x8 vf1 = *(const bf16x8*)&Vs[(dt * 16 + l15) * 64 + 32 + quad * 8];
            cacc[dt] = MFMA_BF16(pf0, vf0, cacc[dt]);
            cacc[dt] = MFMA_BF16(pf1, vf1, cacc[dt]);
        }
    }

    // ---- store ctx [B, S, 768] bf16 ----
    const size_t obase = ((size_t)b * 256) * 768 + (size_t)h * 64;
    #pragma unroll
    for (int dt = 0; dt < 4; ++dt) {
        #pragma unroll
        for (int r = 0; r < 4; ++r) {
            int s = qt * 64 + w * 16 + quad * 4 + r;
            int d = dt * 16 + l15;
            ctx[obase + (size_t)s * 768 + d] = (bf16)cacc[dt][r];
        }
    }
}

extern "C" void kernel_launch(void* const* d_in, const int* in_sizes, int n_in,
                              void* d_out, int out_size, void* d_ws, size_t ws_size,
                              hipStream_t stream) {
    (void)in_sizes; (void)n_in; (void)out_size; (void)ws_size;
    const float* q     = (const float*)d_in[0];
    const float* k     = (const float*)d_in[1];
    const float* v     = (const float*)d_in[2];
    const float* Wq    = (const float*)d_in[3];
    const float* bq    = (const float*)d_in[4];
    const float* Wk    = (const float*)d_in[5];
    const float* bk    = (const float*)d_in[6];
    const float* Wv    = (const float*)d_in[7];
    const float* bv    = (const float*)d_in[8];
    const float* Wo    = (const float*)d_in[9];
    const float* bo    = (const float*)d_in[10];
    const float* table = (const float*)d_in[11];

    const size_t NE = (size_t)128 * 256 * 768;
    bf16* qh  = (bf16*)d_ws;
    bf16* kh  = qh + NE;
    bf16* vh  = kh + NE;        // reused as ctx after transpose_v consumes it
    bf16* vt  = vh + NE;
    bf16* ctx = vh;
    float* out = (float*)d_out;

    dim3 blk(256);
    gemm_qkv<<<dim3(256, 6, 3), blk, 0, stream>>>(q, k, v, Wq, Wk, Wv, bq, bk, bv, qh);
    transpose_v<<<dim3(4, 12, 128), blk, 0, stream>>>(vh, vt);
    attn_kernel<<<dim3(4, 12, 128), blk, 0, stream>>>(qh, kh, vt, table, ctx);
    gemm_out<<<dim3(256, 6), blk, 0, stream>>>(ctx, Wo, bo, out);
}

// Round 3
// 708.986 us; speedup vs baseline: 1.1048x; 1.0426x over previous
//
#include <hip/hip_runtime.h>

// ---------------------------------------------------------------------------
// AttentionRelativeBias: B=128, S=256, D=768, H=12, DH=64, window 8x8 (=64 tok)
// Round 3: make both GEMMs pure-bf16 global_load_lds DMA (fire-and-forget,
// un-sinkable by the scheduler) by pre-converting fp32 inputs to bf16 once.
// Scratch juggling (NO extra ws):
//   d_out (96MB = exactly 2 x Xb): bf16 X copies (q,k then v)
//   vt region: bf16 Wq/Wk/Wv until transpose_v overwrites it
//   qh region: bf16 Wo after attn is done
// GEMM core: 128x128xBK64, dbuf LDS (64KB), 1 barrier/K-step (implicit
// vmcnt(0) drains DMA issued pre-compute), rule-21 swizzle (inverse-swizzled
// DMA source + swizzled ds_read, verified in R1), bijective XCD-chunked
// block swizzle so the 6 n-tiles sharing A-rows are L2-co-resident.
// ---------------------------------------------------------------------------

typedef __bf16 bf16;
typedef __bf16 bf16x8 __attribute__((ext_vector_type(8)));
typedef float  f32x4  __attribute__((ext_vector_type(4)));

#define MFMA_BF16(a, b, c) __builtin_amdgcn_mfma_f32_16x16x32_bf16((a), (b), (c), 0, 0, 0)

__device__ __forceinline__ void gld16(const void* g, void* l) {
    __builtin_amdgcn_global_load_lds(
        (const __attribute__((address_space(1))) void*)g,
        (__attribute__((address_space(3))) void*)l, 16, 0, 0);
}

__device__ __forceinline__ bf16x8 pack8(f32x4 lo, f32x4 hi) {
    bf16x8 r;
    r[0] = (bf16)lo[0]; r[1] = (bf16)lo[1]; r[2] = (bf16)lo[2]; r[3] = (bf16)lo[3];
    r[4] = (bf16)hi[0]; r[5] = (bf16)hi[1]; r[6] = (bf16)hi[2]; r[7] = (bf16)hi[3];
    return r;
}

// LDS tile [128 rows][8 granules of 8 bf16]; granule c of row r sits at slot
// c ^ (r&7). DMA writes linear (slot s holds source granule s^(r&7)); reads
// XOR the same way. ds_read_b128: 16 lanes -> 8 slots x 2 lanes = 2-way = free.
__device__ __forceinline__ int swz8(int row, int g) { return g ^ (row & 7); }

// ---------------- fp32 -> bf16 conversion (pure BW) ------------------------
__global__ __launch_bounds__(256)
void cvt_f32_bf16(const float* __restrict__ src, bf16* __restrict__ dst, int ngroups)
{
    int i = blockIdx.x * 256 + threadIdx.x;
    const int stride = gridDim.x * 256;
    for (; i < ngroups; i += stride) {
        const f32x4* s = (const f32x4*)(src + (size_t)i * 8);
        *(bf16x8*)(dst + (size_t)i * 8) = pack8(s[0], s[1]);
    }
}

// ---------------- bf16 GEMM core (QKV projection epilogue) -----------------
// Y = X @ W^T + b ; X bf16 [32768,768], Wb bf16 [768,768] (row=out,col=in)
// out bf16 [B,H,S,DH] for one z. Grid: 1536 blocks (256 m-tiles x 6 n-tiles).
__global__ __launch_bounds__(256)
void gemm_qkv_b(const bf16* __restrict__ X, const bf16* __restrict__ Wb,
                const float* __restrict__ bias, bf16* __restrict__ out)
{
    __shared__ bf16 As[2][128 * 64];   // 32 KB dbuf
    __shared__ bf16 Bs[2][128 * 64];   // 32 KB dbuf -> 64 KB total, 2 blk/CU

    // bijective XCD-chunked swizzle: 1536 % 8 == 0; each XCD owns a
    // contiguous m-range, its 6 n-tiles adjacent in time -> A L2-resident.
    const int wg  = blockIdx.x;
    const int pos = wg >> 3;
    const int mi  = (wg & 7) * 32 + pos / 6;
    const int ni  = pos % 6;
    const int m0  = mi * 128;
    const int n0  = ni * 128;

    const int tid  = threadIdx.x;
    const int w    = tid >> 6;
    const int lane = tid & 63;
    const int quad = lane >> 4;
    const int l15  = lane & 15;
    const int wr   = (w >> 1) * 64;
    const int wc   = (w & 1) * 64;

    f32x4 acc[4][4] = {};

    auto stage = [&](int buf, int k0) {
        #pragma unroll
        for (int p = 0; p < 4; ++p) {
            int g = p * 256 + tid;
            int row = g >> 3, slot = g & 7;
            int cg  = slot ^ (row & 7);      // inverse-swizzled source granule
            gld16(X  + (size_t)(m0 + row) * 768 + k0 + cg * 8, (char*)&As[buf][0] + g * 16);
            gld16(Wb + (size_t)(n0 + row) * 768 + k0 + cg * 8, (char*)&Bs[buf][0] + g * 16);
        }
    };
    auto compute = [&](int buf) {
        #pragma unroll
        for (int kk = 0; kk < 2; ++kk) {
            bf16x8 af[4], bfr[4];
            #pragma unroll
            for (int mt = 0; mt < 4; ++mt) {
                int row = wr + mt * 16 + l15;
                af[mt] = *(const bf16x8*)&As[buf][row * 64 + swz8(row, kk * 4 + quad) * 8];
            }
            #pragma unroll
            for (int nt = 0; nt < 4; ++nt) {
                int row = wc + nt * 16 + l15;
                bfr[nt] = *(const bf16x8*)&Bs[buf][row * 64 + swz8(row, kk * 4 + quad) * 8];
            }
            #pragma unroll
            for (int mt = 0; mt < 4; ++mt)
                #pragma unroll
                for (int nt = 0; nt < 4; ++nt)
                    acc[mt][nt] = MFMA_BF16(af[mt], bfr[nt], acc[mt][nt]);
        }
    };

    stage(0, 0);
    __syncthreads();                     // drains prologue DMA (vmcnt 0)
    int cur = 0;
    for (int kt = 0; kt < 11; ++kt) {
        stage(cur ^ 1, (kt + 1) * 64);   // DMA issue: fire-and-forget
        compute(cur);                    // latency hides under ds_read+MFMA
        __syncthreads();                 // single barrier: drains DMA + LDS
        cur ^= 1;
    }
    compute(cur);

    #pragma unroll
    for (int mt = 0; mt < 4; ++mt) {
        #pragma unroll
        for (int nt = 0; nt < 4; ++nt) {
            int gn = n0 + wc + nt * 16 + l15;
            float bv = bias[gn];
            int h = gn >> 6, d = gn & 63;
            #pragma unroll
            for (int r = 0; r < 4; ++r) {
                int gm = m0 + wr + mt * 16 + quad * 4 + r;
                int b = gm >> 8, s = gm & 255;
                out[(((size_t)(b * 12 + h) << 8) + s) * 64 + d] = (bf16)(acc[mt][nt][r] + bv);
            }
        }
    }
}

// ---------------- bf16 GEMM core (output projection epilogue) --------------
// out fp32 [32768,768] = ctx(bf16) @ Wo_b^T + bo
__global__ __launch_bounds__(256)
void gemm_out_b(const bf16* __restrict__ X, const bf16* __restrict__ Wb,
                const float* __restrict__ bias, float* __restrict__ out)
{
    __shared__ bf16 As[2][128 * 64];
    __shared__ bf16 Bs[2][128 * 64];

    const int wg  = blockIdx.x;
    const int pos = wg >> 3;
    const int mi  = (wg & 7) * 32 + pos / 6;
    const int ni  = pos % 6;
    const int m0  = mi * 128;
    const int n0  = ni * 128;

    const int tid  = threadIdx.x;
    const int w    = tid >> 6;
    const int lane = tid & 63;
    const int quad = lane >> 4;
    const int l15  = lane & 15;
    const int wr   = (w >> 1) * 64;
    const int wc   = (w & 1) * 64;

    f32x4 acc[4][4] = {};

    auto stage = [&](int buf, int k0) {
        #pragma unroll
        for (int p = 0; p < 4; ++p) {
            int g = p * 256 + tid;
            int row = g >> 3, slot = g & 7;
            int cg  = slot ^ (row & 7);
            gld16(X  + (size_t)(m0 + row) * 768 + k0 + cg * 8, (char*)&As[buf][0] + g * 16);
            gld16(Wb + (size_t)(n0 + row) * 768 + k0 + cg * 8, (char*)&Bs[buf][0] + g * 16);
        }
    };
    auto compute = [&](int buf) {
        #pragma unroll
        for (int kk = 0; kk < 2; ++kk) {
            bf16x8 af[4], bfr[4];
            #pragma unroll
            for (int mt = 0; mt < 4; ++mt) {
                int row = wr + mt * 16 + l15;
                af[mt] = *(const bf16x8*)&As[buf][row * 64 + swz8(row, kk * 4 + quad) * 8];
            }
            #pragma unroll
            for (int nt = 0; nt < 4; ++nt) {
                int row = wc + nt * 16 + l15;
                bfr[nt] = *(const bf16x8*)&Bs[buf][row * 64 + swz8(row, kk * 4 + quad) * 8];
            }
            #pragma unroll
            for (int mt = 0; mt < 4; ++mt)
                #pragma unroll
                for (int nt = 0; nt < 4; ++nt)
                    acc[mt][nt] = MFMA_BF16(af[mt], bfr[nt], acc[mt][nt]);
        }
    };

    stage(0, 0);
    __syncthreads();
    int cur = 0;
    for (int kt = 0; kt < 11; ++kt) {
        stage(cur ^ 1, (kt + 1) * 64);
        compute(cur);
        __syncthreads();
        cur ^= 1;
    }
    compute(cur);

    #pragma unroll
    for (int mt = 0; mt < 4; ++mt) {
        #pragma unroll
        for (int nt = 0; nt < 4; ++nt) {
            int gn = n0 + wc + nt * 16 + l15;
            float bv = bias[gn];
            #pragma unroll
            for (int r = 0; r < 4; ++r) {
                int gm = m0 + wr + mt * 16 + quad * 4 + r;
                out[(size_t)gm * 768 + gn] = acc[mt][nt][r] + bv;
            }
        }
    }
}

// ---------------- V transpose: [B,H,S,DH] -> [B,H,DH,S] -------------------
__global__ __launch_bounds__(256)
void transpose_v(const bf16* __restrict__ vh, bf16* __restrict__ vt)
{
    __shared__ bf16 Ts[64 * 65];
    const int qt = blockIdx.x, h = blockIdx.y, b = blockIdx.z;
    const bf16* src = vh + ((size_t)(b * 12 + h) * 256 + qt * 64) * 64;
    bf16* dst = vt + (size_t)(b * 12 + h) * 64 * 256;

    const int tid = threadIdx.x;
    {
        int row = tid >> 2, c0 = (tid & 3) * 16;
        bf16x8 v0 = *(const bf16x8*)(src + row * 64 + c0);
        bf16x8 v1 = *(const bf16x8*)(src + row * 64 + c0 + 8);
        #pragma unroll
        for (int i = 0; i < 8; ++i) {
            Ts[row * 65 + c0 + i]     = v0[i];
            Ts[row * 65 + c0 + 8 + i] = v1[i];
        }
    }
    __syncthreads();
    {
        int d = tid >> 2, j0 = (tid & 3) * 16;
        bf16x8 o0, o1;
        #pragma unroll
        for (int i = 0; i < 8; ++i) {
            o0[i] = Ts[(j0 + i) * 65 + d];
            o1[i] = Ts[(j0 + 8 + i) * 65 + d];
        }
        *(bf16x8*)(dst + (size_t)d * 256 + qt * 64 + j0)     = o0;
        *(bf16x8*)(dst + (size_t)d * 256 + qt * 64 + j0 + 8) = o1;
    }
}

// ---------------- attention ------------------------------------------------
__global__ __launch_bounds__(256)
void attn_kernel(const bf16* __restrict__ qh, const bf16* __restrict__ kh,
                 const bf16* __restrict__ vt, const float* __restrict__ table,
                 bf16* __restrict__ ctx)
{
    __shared__ bf16 Qs[64 * 64];
    __shared__ bf16 Ks[64 * 64];
    __shared__ bf16 Vs[64 * 64];
    __shared__ bf16 Ps[4 * 16 * 72];
    __shared__ bf16 Bsh[64 * 68];

    const int tid  = threadIdx.x;
    const int qt   = blockIdx.x;
    const int h    = blockIdx.y;
    const int b    = blockIdx.z;
    const int w    = tid >> 6;
    const int lane = tid & 63;
    const int quad = lane >> 4;
    const int l15  = lane & 15;

    const size_t bh = (size_t)(b * 12 + h) * 256 * 64;
    const bf16* Qg  = qh + bh + (size_t)qt * 64 * 64;
    const bf16* Kg  = kh + bh;
    const bf16* Vtg = vt + bh;   // [64][256]

    #pragma unroll
    for (int p = 0; p < 2; ++p) {
        int g = p * 256 + tid;
        gld16(Qg + (size_t)(g >> 3) * 64 + (g & 7) * 8, (char*)Qs + g * 16);
    }
    {
        int i = tid >> 2, j0 = (tid & 3) * 16;
        int ai = i >> 3, aj = i & 7;
        #pragma unroll
        for (int jj = 0; jj < 16; ++jj) {
            int j = j0 + jj;
            int idx = (ai - (j >> 3) + 7) * 15 + (aj - (j & 7) + 7);
            Bsh[i * 68 + j] = (bf16)table[idx * 12 + h];
        }
    }

    // ---- QK^T over 4 key chunks ----
    f32x4 sacc[16] = {};
    bf16x8 qf0, qf1;
    for (int c = 0; c < 4; ++c) {
        __syncthreads();
        #pragma unroll
        for (int p = 0; p < 2; ++p) {
            int g = p * 256 + tid;
            gld16(Kg + (size_t)(c * 64 + (g >> 3)) * 64 + (g & 7) * 8, (char*)Ks + g * 16);
        }
        __syncthreads();
        if (c == 0) {
            qf0 = *(const bf16x8*)&Qs[(w * 16 + l15) * 64 + quad * 8];
            qf1 = *(const bf16x8*)&Qs[(w * 16 + l15) * 64 + 32 + quad * 8];
        }
        #pragma unroll
        for (int jtl = 0; jtl < 4; ++jtl) {
            bf16x8 kf0 = *(const bf16x8*)&Ks[(jtl * 16 + l15) * 64 + quad * 8];
            bf16x8 kf1 = *(const bf16x8*)&Ks[(jtl * 16 + l15) * 64 + 32 + quad * 8];
            sacc[c * 4 + jtl] = MFMA_BF16(qf0, kf0, sacc[c * 4 + jtl]);
            sacc[c * 4 + jtl] = MFMA_BF16(qf1, kf1, sacc[c * 4 + jtl]);
        }
    }

    // ---- softmax ----
    const int browbase = w * 16 + quad * 4;
    float p[16][4];
    #pragma unroll
    for (int jt = 0; jt < 16; ++jt) {
        int jcol = ((jt * 16) & 63) + l15;
        #pragma unroll
        for (int r = 0; r < 4; ++r)
            p[jt][r] = sacc[jt][r] * 0.125f + (float)Bsh[(browbase + r) * 68 + jcol];
    }
    float invl[4];
    #pragma unroll
    for (int r = 0; r < 4; ++r) {
        float m = p[0][r];
        #pragma unroll
        for (int jt = 1; jt < 16; ++jt) m = fmaxf(m, p[jt][r]);
        #pragma unroll
        for (int off = 1; off < 16; off <<= 1)
            m = fmaxf(m, __shfl_xor(m, off, 64));
        float s = 0.f;
        #pragma unroll
        for (int jt = 0; jt < 16; ++jt) {
            p[jt][r] = __expf(p[jt][r] - m);
            s += p[jt][r];
        }
        #pragma unroll
        for (int off = 1; off < 16; off <<= 1)
            s += __shfl_xor(s, off, 64);
        invl[r] = 1.0f / s;
    }

    // ---- PV over 4 key chunks ----
    f32x4 cacc[4] = {};
    bf16* Pw = &Ps[w * 16 * 72];
    for (int c = 0; c < 4; ++c) {
        __syncthreads();
        #pragma unroll
        for (int pp = 0; pp < 2; ++pp) {
            int g = pp * 256 + tid;
            gld16(Vtg + (size_t)(g >> 3) * 256 + c * 64 + (g & 7) * 8, (char*)Vs + g * 16);
        }
        #pragma unroll
        for (int jtl = 0; jtl < 4; ++jtl) {
            int jt = c * 4 + jtl;
            #pragma unroll
            for (int r = 0; r < 4; ++r)
                Pw[(quad * 4 + r) * 72 + jtl * 16 + l15] = (bf16)(p[jt][r] * invl[r]);
        }
        __syncthreads();
        bf16x8 pf0 = *(const bf16x8*)&Pw[l15 * 72 + quad * 8];
        bf16x8 pf1 = *(const bf16x8*)&Pw[l15 * 72 + 32 + quad * 8];
        #pragma unroll
        for (int dt = 0; dt < 4; ++dt) {
            bf16x8 vf0 = *(const bf16x8*)&Vs[(dt * 16 + l15) * 64 + quad * 8];
            bf16x8 vf1 = *(const bf16x8*)&Vs[(dt * 16 + l15) * 64 + 32 + quad * 8];
            cacc[dt] = MFMA_BF16(pf0, vf0, cacc[dt]);
            cacc[dt] = MFMA_BF16(pf1, vf1, cacc[dt]);
        }
    }

    const size_t obase = ((size_t)b * 256) * 768 + (size_t)h * 64;
    #pragma unroll
    for (int dt = 0; dt < 4; ++dt) {
        #pragma unroll
        for (int r = 0; r < 4; ++r) {
            int s = qt * 64 + w * 16 + quad * 4 + r;
            int d = dt * 16 + l15;
            ctx[obase + (size_t)s * 768 + d] = (bf16)cacc[dt][r];
        }
    }
}

extern "C" void kernel_launch(void* const* d_in, const int* in_sizes, int n_in,
                              void* d_out, int out_size, void* d_ws, size_t ws_size,
                              hipStream_t stream) {
    (void)in_sizes; (void)n_in; (void)out_size; (void)ws_size;
    const float* q     = (const float*)d_in[0];
    const float* k     = (const float*)d_in[1];
    const float* v     = (const float*)d_in[2];
    const float* Wq    = (const float*)d_in[3];
    const float* bq    = (const float*)d_in[4];
    const float* Wk    = (const float*)d_in[5];
    const float* bk    = (const float*)d_in[6];
    const float* Wv    = (const float*)d_in[7];
    const float* bv    = (const float*)d_in[8];
    const float* Wo    = (const float*)d_in[9];
    const float* bo    = (const float*)d_in[10];
    const float* table = (const float*)d_in[11];

    const size_t NE = (size_t)128 * 256 * 768;   // 25,165,824 elems
    const size_t WE = (size_t)768 * 768;         // 589,824 elems

    // ws: [qh][kh][vh -> ctx][vt]
    bf16* qh  = (bf16*)d_ws;
    bf16* kh  = qh + NE;
    bf16* vh  = kh + NE;
    bf16* vt  = vh + NE;
    bf16* ctx = vh;
    float* out = (float*)d_out;

    // scratch: d_out holds exactly 2 bf16 X copies; vt holds the 3 bf16 W
    // copies until transpose_v overwrites; qh holds Wo_b after attn.
    bf16* xq_b = (bf16*)d_out;           // [0, 50.33MB)
    bf16* xk_b = xq_b + NE;              // [50.33, 100.66MB) == out_size
    bf16* xv_b = xq_b;                   // reuse after gemm z0 done
    bf16* wq_b = vt;
    bf16* wk_b = wq_b + WE;
    bf16* wv_b = wk_b + WE;
    bf16* wo_b = qh;                     // valid only after attn completes

    const int XG = (int)(NE / 8);        // 3,145,728 groups of 8
    const int WG = (int)(WE / 8);        // 73,728 groups

    dim3 blk(256);
    cvt_f32_bf16<<<2048, blk, 0, stream>>>(q,  xq_b, XG);
    cvt_f32_bf16<<<2048, blk, 0, stream>>>(k,  xk_b, XG);
    cvt_f32_bf16<<<288,  blk, 0, stream>>>(Wq, wq_b, WG);
    cvt_f32_bf16<<<288,  blk, 0, stream>>>(Wk, wk_b, WG);
    cvt_f32_bf16<<<288,  blk, 0, stream>>>(Wv, wv_b, WG);

    gemm_qkv_b<<<1536, blk, 0, stream>>>(xq_b, wq_b, bq, qh);
    gemm_qkv_b<<<1536, blk, 0, stream>>>(xk_b, wk_b, bk, kh);
    cvt_f32_bf16<<<2048, blk, 0, stream>>>(v, xv_b, XG);     // xq_b dead now
    gemm_qkv_b<<<1536, blk, 0, stream>>>(xv_b, wv_b, bv, vh);

    transpose_v<<<dim3(4, 12, 128), blk, 0, stream>>>(vh, vt);   // kills w*_b
    attn_kernel<<<dim3(4, 12, 128), blk, 0, stream>>>(qh, kh, vt, table, ctx);

    cvt_f32_bf16<<<288, blk, 0, stream>>>(Wo, wo_b, WG);     // qh dead now
    gemm_out_b<<<1536, blk, 0, stream>>>(ctx, wo_b, bo, out);
}

// Round 4
// 685.503 us; speedup vs baseline: 1.1427x; 1.0343x over previous
//
#include <hip/hip_runtime.h>

// ---------------------------------------------------------------------------
// AttentionRelativeBias: B=128, S=256, D=768, H=12, DH=64, window 8x8 (=64 tok)
// Round 4: attn rework. R3 counters: attn = top dispatch (119us), MfmaUtil
// 8.6%, 2.0e7 bank-conflict cycles (~28% of CU cycles), 16 serial-DMA
// barriers, per-block bias gather. Fix: (1) bias precomputed once to
// biasb[12][64][64] bf16 (dead xk_b scratch), consumed as 16 regs/lane;
// (2) Q/K/V LDS swizzled (rule-21: inverse-swizzled DMA src + XOR read);
// (3) K,V double-buffered with prefetch-before-compute, V[0] issued under
// softmax; (4) V buffers alias K buffers -> LDS 33.2KB -> 4 blocks/CU.
// GEMMs/cvt/transpose unchanged from R3 for clean attribution.
// ---------------------------------------------------------------------------

typedef __bf16 bf16;
typedef __bf16 bf16x8 __attribute__((ext_vector_type(8)));
typedef float  f32x4  __attribute__((ext_vector_type(4)));

#define MFMA_BF16(a, b, c) __builtin_amdgcn_mfma_f32_16x16x32_bf16((a), (b), (c), 0, 0, 0)

__device__ __forceinline__ void gld16(const void* g, void* l) {
    __builtin_amdgcn_global_load_lds(
        (const __attribute__((address_space(1))) void*)g,
        (__attribute__((address_space(3))) void*)l, 16, 0, 0);
}

__device__ __forceinline__ bf16x8 pack8(f32x4 lo, f32x4 hi) {
    bf16x8 r;
    r[0] = (bf16)lo[0]; r[1] = (bf16)lo[1]; r[2] = (bf16)lo[2]; r[3] = (bf16)lo[3];
    r[4] = (bf16)hi[0]; r[5] = (bf16)hi[1]; r[6] = (bf16)hi[2]; r[7] = (bf16)hi[3];
    return r;
}

// LDS tile [rows][8 granules of 8 bf16], row stride 128B; granule c of row r
// at slot c ^ (r&7). DMA dest linear; source granule pre-XOR'd; reads XOR'd.
__device__ __forceinline__ int swz8(int row, int g) { return g ^ (row & 7); }

// ---------------- fp32 -> bf16 conversion (pure BW) ------------------------
__global__ __launch_bounds__(256)
void cvt_f32_bf16(const float* __restrict__ src, bf16* __restrict__ dst, int ngroups)
{
    int i = blockIdx.x * 256 + threadIdx.x;
    const int stride = gridDim.x * 256;
    for (; i < ngroups; i += stride) {
        const f32x4* s = (const f32x4*)(src + (size_t)i * 8);
        *(bf16x8*)(dst + (size_t)i * 8) = pack8(s[0], s[1]);
    }
}

// ---------------- bias expand: table[225][12] -> biasb[12][64][64] bf16 ----
__global__ __launch_bounds__(256)
void bias_expand(const float* __restrict__ table, bf16* __restrict__ biasb)
{
    const int h   = blockIdx.x;        // 12
    const int tid = threadIdx.x;       // 256 threads x 16 elems = 4096
    const int e0  = tid * 16;
    const int i   = e0 >> 6;
    const int j0  = e0 & 63;
    const int ai  = i >> 3, aj = i & 7;
    #pragma unroll
    for (int n = 0; n < 16; ++n) {
        int j = j0 + n;
        int idx = (ai - (j >> 3) + 7) * 15 + (aj - (j & 7) + 7);
        biasb[h * 4096 + i * 64 + j] = (bf16)table[idx * 12 + h];
    }
}

// ---------------- bf16 GEMM core (QKV projection epilogue) -----------------
__global__ __launch_bounds__(256)
void gemm_qkv_b(const bf16* __restrict__ X, const bf16* __restrict__ Wb,
                const float* __restrict__ bias, bf16* __restrict__ out)
{
    __shared__ bf16 As[2][128 * 64];
    __shared__ bf16 Bs[2][128 * 64];

    const int wg  = blockIdx.x;
    const int pos = wg >> 3;
    const int mi  = (wg & 7) * 32 + pos / 6;
    const int ni  = pos % 6;
    const int m0  = mi * 128;
    const int n0  = ni * 128;

    const int tid  = threadIdx.x;
    const int w    = tid >> 6;
    const int lane = tid & 63;
    const int quad = lane >> 4;
    const int l15  = lane & 15;
    const int wr   = (w >> 1) * 64;
    const int wc   = (w & 1) * 64;

    f32x4 acc[4][4] = {};

    auto stage = [&](int buf, int k0) {
        #pragma unroll
        for (int p = 0; p < 4; ++p) {
            int g = p * 256 + tid;
            int row = g >> 3, slot = g & 7;
            int cg  = slot ^ (row & 7);
            gld16(X  + (size_t)(m0 + row) * 768 + k0 + cg * 8, (char*)&As[buf][0] + g * 16);
            gld16(Wb + (size_t)(n0 + row) * 768 + k0 + cg * 8, (char*)&Bs[buf][0] + g * 16);
        }
    };
    auto compute = [&](int buf) {
        #pragma unroll
        for (int kk = 0; kk < 2; ++kk) {
            bf16x8 af[4], bfr[4];
            #pragma unroll
            for (int mt = 0; mt < 4; ++mt) {
                int row = wr + mt * 16 + l15;
                af[mt] = *(const bf16x8*)&As[buf][row * 64 + swz8(row, kk * 4 + quad) * 8];
            }
            #pragma unroll
            for (int nt = 0; nt < 4; ++nt) {
                int row = wc + nt * 16 + l15;
                bfr[nt] = *(const bf16x8*)&Bs[buf][row * 64 + swz8(row, kk * 4 + quad) * 8];
            }
            #pragma unroll
            for (int mt = 0; mt < 4; ++mt)
                #pragma unroll
                for (int nt = 0; nt < 4; ++nt)
                    acc[mt][nt] = MFMA_BF16(af[mt], bfr[nt], acc[mt][nt]);
        }
    };

    stage(0, 0);
    __syncthreads();
    int cur = 0;
    for (int kt = 0; kt < 11; ++kt) {
        stage(cur ^ 1, (kt + 1) * 64);
        compute(cur);
        __syncthreads();
        cur ^= 1;
    }
    compute(cur);

    #pragma unroll
    for (int mt = 0; mt < 4; ++mt) {
        #pragma unroll
        for (int nt = 0; nt < 4; ++nt) {
            int gn = n0 + wc + nt * 16 + l15;
            float bv = bias[gn];
            int h = gn >> 6, d = gn & 63;
            #pragma unroll
            for (int r = 0; r < 4; ++r) {
                int gm = m0 + wr + mt * 16 + quad * 4 + r;
                int b = gm >> 8, s = gm & 255;
                out[(((size_t)(b * 12 + h) << 8) + s) * 64 + d] = (bf16)(acc[mt][nt][r] + bv);
            }
        }
    }
}

// ---------------- bf16 GEMM core (output projection epilogue) --------------
__global__ __launch_bounds__(256)
void gemm_out_b(const bf16* __restrict__ X, const bf16* __restrict__ Wb,
                const float* __restrict__ bias, float* __restrict__ out)
{
    __shared__ bf16 As[2][128 * 64];
    __shared__ bf16 Bs[2][128 * 64];

    const int wg  = blockIdx.x;
    const int pos = wg >> 3;
    const int mi  = (wg & 7) * 32 + pos / 6;
    const int ni  = pos % 6;
    const int m0  = mi * 128;
    const int n0  = ni * 128;

    const int tid  = threadIdx.x;
    const int w    = tid >> 6;
    const int lane = tid & 63;
    const int quad = lane >> 4;
    const int l15  = lane & 15;
    const int wr   = (w >> 1) * 64;
    const int wc   = (w & 1) * 64;

    f32x4 acc[4][4] = {};

    auto stage = [&](int buf, int k0) {
        #pragma unroll
        for (int p = 0; p < 4; ++p) {
            int g = p * 256 + tid;
            int row = g >> 3, slot = g & 7;
            int cg  = slot ^ (row & 7);
            gld16(X  + (size_t)(m0 + row) * 768 + k0 + cg * 8, (char*)&As[buf][0] + g * 16);
            gld16(Wb + (size_t)(n0 + row) * 768 + k0 + cg * 8, (char*)&Bs[buf][0] + g * 16);
        }
    };
    auto compute = [&](int buf) {
        #pragma unroll
        for (int kk = 0; kk < 2; ++kk) {
            bf16x8 af[4], bfr[4];
            #pragma unroll
            for (int mt = 0; mt < 4; ++mt) {
                int row = wr + mt * 16 + l15;
                af[mt] = *(const bf16x8*)&As[buf][row * 64 + swz8(row, kk * 4 + quad) * 8];
            }
            #pragma unroll
            for (int nt = 0; nt < 4; ++nt) {
                int row = wc + nt * 16 + l15;
                bfr[nt] = *(const bf16x8*)&Bs[buf][row * 64 + swz8(row, kk * 4 + quad) * 8];
            }
            #pragma unroll
            for (int mt = 0; mt < 4; ++mt)
                #pragma unroll
                for (int nt = 0; nt < 4; ++nt)
                    acc[mt][nt] = MFMA_BF16(af[mt], bfr[nt], acc[mt][nt]);
        }
    };

    stage(0, 0);
    __syncthreads();
    int cur = 0;
    for (int kt = 0; kt < 11; ++kt) {
        stage(cur ^ 1, (kt + 1) * 64);
        compute(cur);
        __syncthreads();
        cur ^= 1;
    }
    compute(cur);

    #pragma unroll
    for (int mt = 0; mt < 4; ++mt) {
        #pragma unroll
        for (int nt = 0; nt < 4; ++nt) {
            int gn = n0 + wc + nt * 16 + l15;
            float bv = bias[gn];
            #pragma unroll
            for (int r = 0; r < 4; ++r) {
                int gm = m0 + wr + mt * 16 + quad * 4 + r;
                out[(size_t)gm * 768 + gn] = acc[mt][nt][r] + bv;
            }
        }
    }
}

// ---------------- V transpose: [B,H,S,DH] -> [B,H,DH,S] -------------------
__global__ __launch_bounds__(256)
void transpose_v(const bf16* __restrict__ vh, bf16* __restrict__ vt)
{
    __shared__ bf16 Ts[64 * 65];
    const int qt = blockIdx.x, h = blockIdx.y, b = blockIdx.z;
    const bf16* src = vh + ((size_t)(b * 12 + h) * 256 + qt * 64) * 64;
    bf16* dst = vt + (size_t)(b * 12 + h) * 64 * 256;

    const int tid = threadIdx.x;
    {
        int row = tid >> 2, c0 = (tid & 3) * 16;
        bf16x8 v0 = *(const bf16x8*)(src + row * 64 + c0);
        bf16x8 v1 = *(const bf16x8*)(src + row * 64 + c0 + 8);
        #pragma unroll
        for (int i = 0; i < 8; ++i) {
            Ts[row * 65 + c0 + i]     = v0[i];
            Ts[row * 65 + c0 + 8 + i] = v1[i];
        }
    }
    __syncthreads();
    {
        int d = tid >> 2, j0 = (tid & 3) * 16;
        bf16x8 o0, o1;
        #pragma unroll
        for (int i = 0; i < 8; ++i) {
            o0[i] = Ts[(j0 + i) * 65 + d];
            o1[i] = Ts[(j0 + 8 + i) * 65 + d];
        }
        *(bf16x8*)(dst + (size_t)d * 256 + qt * 64 + j0)     = o0;
        *(bf16x8*)(dst + (size_t)d * 256 + qt * 64 + j0 + 8) = o1;
    }
}

// ---------------- attention ------------------------------------------------
__global__ __launch_bounds__(256)
void attn_kernel(const bf16* __restrict__ qh, const bf16* __restrict__ kh,
                 const bf16* __restrict__ vt, const bf16* __restrict__ biasb,
                 bf16* __restrict__ ctx)
{
    __shared__ bf16 Qs[64 * 64];        // 8 KB, swizzled
    __shared__ bf16 KVs[2][64 * 64];    // 16 KB: K dbuf during QK^T, V dbuf during PV
    __shared__ bf16 Ps[4 * 16 * 72];    // 9.2 KB per-wave P (LD=72, ~2-way free)
    // total 33.2 KB -> 4 blocks/CU

    const int tid  = threadIdx.x;
    const int qt   = blockIdx.x;
    const int h    = blockIdx.y;
    const int b    = blockIdx.z;
    const int w    = tid >> 6;
    const int lane = tid & 63;
    const int quad = lane >> 4;
    const int l15  = lane & 15;

    const size_t bh = (size_t)(b * 12 + h) * 256 * 64;
    const bf16* Qg  = qh + bh + (size_t)qt * 64 * 64;
    const bf16* Kg  = kh + bh;           // [256][64]
    const bf16* Vtg = vt + bh;           // [64][256]

    // stage a [64 rows][64 cols] tile (row stride rs elems) with
    // inverse-swizzled source granules, linear LDS dest (rule-21 pair).
    auto stageT = [&](const bf16* src, size_t rs, bf16* dstLds) {
        #pragma unroll
        for (int p = 0; p < 2; ++p) {
            int g = p * 256 + tid;
            int row = g >> 3, slot = g & 7;
            int cg  = slot ^ (row & 7);
            gld16(src + (size_t)row * rs + cg * 8, (char*)dstLds + g * 16);
        }
    };

    // bias registers: col pattern repeats mod 64 -> 16 scalars per lane
    const int browbase = w * 16 + quad * 4;
    const bf16* bb = biasb + h * 4096;
    float bregs[4][4];
    #pragma unroll
    for (int r = 0; r < 4; ++r)
        #pragma unroll
        for (int c4 = 0; c4 < 4; ++c4)
            bregs[r][c4] = (float)bb[(browbase + r) * 64 + c4 * 16 + l15];

    stageT(Qg, 64, Qs);
    stageT(Kg, 64, KVs[0]);
    __syncthreads();                               // drains Q + K0 DMA

    // Q fragments (read once)
    bf16x8 qf0, qf1;
    {
        int qrow = w * 16 + l15;
        qf0 = *(const bf16x8*)&Qs[qrow * 64 + swz8(qrow, quad) * 8];
        qf1 = *(const bf16x8*)&Qs[qrow * 64 + swz8(qrow, 4 + quad) * 8];
    }

    // ---- QK^T over 4 key chunks, K double-buffered with prefetch ----
    f32x4 sacc[16] = {};
    for (int c = 0; c < 4; ++c) {
        if (c < 3) stageT(Kg + (size_t)(c + 1) * 64 * 64, 64, KVs[(c + 1) & 1]);
        const bf16* Kb = KVs[c & 1];
        #pragma unroll
        for (int jtl = 0; jtl < 4; ++jtl) {
            int krow = jtl * 16 + l15;
            bf16x8 kf0 = *(const bf16x8*)&Kb[krow * 64 + swz8(krow, quad) * 8];
            bf16x8 kf1 = *(const bf16x8*)&Kb[krow * 64 + swz8(krow, 4 + quad) * 8];
            sacc[c * 4 + jtl] = MFMA_BF16(qf0, kf0, sacc[c * 4 + jtl]);
            sacc[c * 4 + jtl] = MFMA_BF16(qf1, kf1, sacc[c * 4 + jtl]);
        }
        __syncthreads();                           // drains K[c+1] DMA; rotates
    }

    // prefetch V chunk 0 now; latency hides under the softmax VALU phase
    stageT(Vtg, 256, KVs[0]);

    // ---- softmax (bias from registers) ----
    float p[16][4];
    #pragma unroll
    for (int jt = 0; jt < 16; ++jt)
        #pragma unroll
        for (int r = 0; r < 4; ++r)
            p[jt][r] = sacc[jt][r] * 0.125f + bregs[r][jt & 3];
    float invl[4];
    #pragma unroll
    for (int r = 0; r < 4; ++r) {
        float m = p[0][r];
        #pragma unroll
        for (int jt = 1; jt < 16; ++jt) m = fmaxf(m, p[jt][r]);
        #pragma unroll
        for (int off = 1; off < 16; off <<= 1)
            m = fmaxf(m, __shfl_xor(m, off, 64));
        float s = 0.f;
        #pragma unroll
        for (int jt = 0; jt < 16; ++jt) {
            p[jt][r] = __expf(p[jt][r] - m);
            s += p[jt][r];
        }
        #pragma unroll
        for (int off = 1; off < 16; off <<= 1)
            s += __shfl_xor(s, off, 64);
        invl[r] = 1.0f / s;
    }

    // ---- PV over 4 key chunks, V double-buffered with prefetch ----
    f32x4 cacc[4] = {};
    bf16* Pw = &Ps[w * 16 * 72];
    for (int c = 0; c < 4; ++c) {
        #pragma unroll
        for (int jtl = 0; jtl < 4; ++jtl) {
            int jt = c * 4 + jtl;
            #pragma unroll
            for (int r = 0; r < 4; ++r)
                Pw[(quad * 4 + r) * 72 + jtl * 16 + l15] = (bf16)(p[jt][r] * invl[r]);
        }
        __syncthreads();                           // drains V[c] DMA + P writes
        if (c < 3) stageT(Vtg + (size_t)(c + 1) * 64, 256, KVs[(c + 1) & 1]);
        const bf16* Vb = KVs[c & 1];
        bf16x8 pf0 = *(const bf16x8*)&Pw[l15 * 72 + quad * 8];
        bf16x8 pf1 = *(const bf16x8*)&Pw[l15 * 72 + 32 + quad * 8];
        #pragma unroll
        for (int dt = 0; dt < 4; ++dt) {
            int vrow = dt * 16 + l15;
            bf16x8 vf0 = *(const bf16x8*)&Vb[vrow * 64 + swz8(vrow, quad) * 8];
            bf16x8 vf1 = *(const bf16x8*)&Vb[vrow * 64 + swz8(vrow, 4 + quad) * 8];
            cacc[dt] = MFMA_BF16(pf0, vf0, cacc[dt]);
            cacc[dt] = MFMA_BF16(pf1, vf1, cacc[dt]);
        }
    }

    // ---- store ctx [B, S, 768] bf16 ----
    const size_t obase = ((size_t)b * 256) * 768 + (size_t)h * 64;
    #pragma unroll
    for (int dt = 0; dt < 4; ++dt) {
        #pragma unroll
        for (int r = 0; r < 4; ++r) {
            int s = qt * 64 + w * 16 + quad * 4 + r;
            int d = dt * 16 + l15;
            ctx[obase + (size_t)s * 768 + d] = (bf16)cacc[dt][r];
        }
    }
}

extern "C" void kernel_launch(void* const* d_in, const int* in_sizes, int n_in,
                              void* d_out, int out_size, void* d_ws, size_t ws_size,
                              hipStream_t stream) {
    (void)in_sizes; (void)n_in; (void)out_size; (void)ws_size;
    const float* q     = (const float*)d_in[0];
    const float* k     = (const float*)d_in[1];
    const float* v     = (const float*)d_in[2];
    const float* Wq    = (const float*)d_in[3];
    const float* bq    = (const float*)d_in[4];
    const float* Wk    = (const float*)d_in[5];
    const float* bk    = (const float*)d_in[6];
    const float* Wv    = (const float*)d_in[7];
    const float* bv    = (const float*)d_in[8];
    const float* Wo    = (const float*)d_in[9];
    const float* bo    = (const float*)d_in[10];
    const float* table = (const float*)d_in[11];

    const size_t NE = (size_t)128 * 256 * 768;   // 25,165,824 elems
    const size_t WE = (size_t)768 * 768;

    bf16* qh  = (bf16*)d_ws;
    bf16* kh  = qh + NE;
    bf16* vh  = kh + NE;
    bf16* vt  = vh + NE;
    bf16* ctx = vh;
    float* out = (float*)d_out;

    // scratch in d_out: 2 bf16 X copies; biasb lives in xk_b region after
    // the k-GEMM consumes it (96KB << 50MB).
    bf16* xq_b  = (bf16*)d_out;
    bf16* xk_b  = xq_b + NE;
    bf16* xv_b  = xq_b;                  // reuse after q-GEMM done
    bf16* biasb = xk_b;                  // valid after k-GEMM done
    bf16* wq_b  = vt;
    bf16* wk_b  = wq_b + WE;
    bf16* wv_b  = wk_b + WE;
    bf16* wo_b  = qh;                    // valid after attn completes

    const int XG = (int)(NE / 8);
    const int WG = (int)(WE / 8);

    dim3 blk(256);
    cvt_f32_bf16<<<2048, blk, 0, stream>>>(q,  xq_b, XG);
    cvt_f32_bf16<<<2048, blk, 0, stream>>>(k,  xk_b, XG);
    cvt_f32_bf16<<<288,  blk, 0, stream>>>(Wq, wq_b, WG);
    cvt_f32_bf16<<<288,  blk, 0, stream>>>(Wk, wk_b, WG);
    cvt_f32_bf16<<<288,  blk, 0, stream>>>(Wv, wv_b, WG);

    gemm_qkv_b<<<1536, blk, 0, stream>>>(xq_b, wq_b, bq, qh);
    gemm_qkv_b<<<1536, blk, 0, stream>>>(xk_b, wk_b, bk, kh);
    bias_expand<<<12, blk, 0, stream>>>(table, biasb);       // xk_b dead now
    cvt_f32_bf16<<<2048, blk, 0, stream>>>(v, xv_b, XG);     // xq_b dead now
    gemm_qkv_b<<<1536, blk, 0, stream>>>(xv_b, wv_b, bv, vh);

    transpose_v<<<dim3(4, 12, 128), blk, 0, stream>>>(vh, vt);   // kills w*_b
    attn_kernel<<<dim3(4, 12, 128), blk, 0, stream>>>(qh, kh, vt, biasb, ctx);

    cvt_f32_bf16<<<288, blk, 0, stream>>>(Wo, wo_b, WG);     // qh dead now
    gemm_out_b<<<1536, blk, 0, stream>>>(ctx, wo_b, bo, out);
}

// Round 5
// 656.642 us; speedup vs baseline: 1.1929x; 1.0440x over previous
//
#include <hip/hip_runtime.h>

// ---------------------------------------------------------------------------
// AttentionRelativeBias: B=128, S=256, D=768, H=12, DH=64, window 8x8 (=64 tok)
// Round 5: GEMM TLP upgrade. R4 accounting: 4 GEMMs ~ 350us (~430 TF each) =
// dominant cost; 2-phase drain (m233: ~72% stage+vmcnt+barrier) hidden by only
// 8 waves/CU (occ 22%). Fix: same 128x128 tile + 64KB dbuf LDS (2 blk/CU),
// but 512 threads / 8 waves per block -> 16 waves/CU. Per-wave out 64x32.
// Attn/cvt/transpose/bias unchanged from R4 for clean attribution.
// ---------------------------------------------------------------------------

typedef __bf16 bf16;
typedef __bf16 bf16x8 __attribute__((ext_vector_type(8)));
typedef float  f32x4  __attribute__((ext_vector_type(4)));

#define MFMA_BF16(a, b, c) __builtin_amdgcn_mfma_f32_16x16x32_bf16((a), (b), (c), 0, 0, 0)

__device__ __forceinline__ void gld16(const void* g, void* l) {
    __builtin_amdgcn_global_load_lds(
        (const __attribute__((address_space(1))) void*)g,
        (__attribute__((address_space(3))) void*)l, 16, 0, 0);
}

__device__ __forceinline__ bf16x8 pack8(f32x4 lo, f32x4 hi) {
    bf16x8 r;
    r[0] = (bf16)lo[0]; r[1] = (bf16)lo[1]; r[2] = (bf16)lo[2]; r[3] = (bf16)lo[3];
    r[4] = (bf16)hi[0]; r[5] = (bf16)hi[1]; r[6] = (bf16)hi[2]; r[7] = (bf16)hi[3];
    return r;
}

// LDS tile [rows][8 granules of 8 bf16], row stride 128B; granule c of row r
// at slot c ^ (r&7). DMA dest linear; source granule pre-XOR'd; reads XOR'd.
__device__ __forceinline__ int swz8(int row, int g) { return g ^ (row & 7); }

// ---------------- fp32 -> bf16 conversion (pure BW) ------------------------
__global__ __launch_bounds__(256)
void cvt_f32_bf16(const float* __restrict__ src, bf16* __restrict__ dst, int ngroups)
{
    int i = blockIdx.x * 256 + threadIdx.x;
    const int stride = gridDim.x * 256;
    for (; i < ngroups; i += stride) {
        const f32x4* s = (const f32x4*)(src + (size_t)i * 8);
        *(bf16x8*)(dst + (size_t)i * 8) = pack8(s[0], s[1]);
    }
}

// ---------------- bias expand: table[225][12] -> biasb[12][64][64] bf16 ----
__global__ __launch_bounds__(256)
void bias_expand(const float* __restrict__ table, bf16* __restrict__ biasb)
{
    const int h   = blockIdx.x;        // 12
    const int tid = threadIdx.x;       // 256 threads x 16 elems = 4096
    const int e0  = tid * 16;
    const int i   = e0 >> 6;
    const int j0  = e0 & 63;
    const int ai  = i >> 3, aj = i & 7;
    #pragma unroll
    for (int n = 0; n < 16; ++n) {
        int j = j0 + n;
        int idx = (ai - (j >> 3) + 7) * 15 + (aj - (j & 7) + 7);
        biasb[h * 4096 + i * 64 + j] = (bf16)table[idx * 12 + h];
    }
}

// ---------------- bf16 GEMM core (QKV projection epilogue) -----------------
// 512 threads = 8 waves (2M x 4N), per-wave output 64x32, acc[4][2].
__global__ __launch_bounds__(512, 4)
void gemm_qkv_b(const bf16* __restrict__ X, const bf16* __restrict__ Wb,
                const float* __restrict__ bias, bf16* __restrict__ out)
{
    __shared__ bf16 As[2][128 * 64];   // 32 KB dbuf
    __shared__ bf16 Bs[2][128 * 64];   // 32 KB dbuf -> 64 KB, 2 blk/CU, 16 w/CU

    const int wg  = blockIdx.x;
    const int pos = wg >> 3;
    const int mi  = (wg & 7) * 32 + pos / 6;
    const int ni  = pos % 6;
    const int m0  = mi * 128;
    const int n0  = ni * 128;

    const int tid  = threadIdx.x;
    const int w    = tid >> 6;
    const int lane = tid & 63;
    const int quad = lane >> 4;
    const int l15  = lane & 15;
    const int wr   = (w >> 2) * 64;    // 2 wave-rows x 64
    const int wc   = (w & 3) * 32;     // 4 wave-cols x 32

    f32x4 acc[4][2] = {};

    auto stage = [&](int buf, int k0) {
        #pragma unroll
        for (int p = 0; p < 2; ++p) {
            int g = p * 512 + tid;               // 1024 granules per operand
            int row = g >> 3, slot = g & 7;
            int cg  = slot ^ (row & 7);          // inverse-swizzled source
            gld16(X  + (size_t)(m0 + row) * 768 + k0 + cg * 8, (char*)&As[buf][0] + g * 16);
            gld16(Wb + (size_t)(n0 + row) * 768 + k0 + cg * 8, (char*)&Bs[buf][0] + g * 16);
        }
    };
    auto compute = [&](int buf) {
        #pragma unroll
        for (int kk = 0; kk < 2; ++kk) {
            bf16x8 af[4], bfr[2];
            #pragma unroll
            for (int mt = 0; mt < 4; ++mt) {
                int row = wr + mt * 16 + l15;
                af[mt] = *(const bf16x8*)&As[buf][row * 64 + swz8(row, kk * 4 + quad) * 8];
            }
            #pragma unroll
            for (int nt = 0; nt < 2; ++nt) {
                int row = wc + nt * 16 + l15;
                bfr[nt] = *(const bf16x8*)&Bs[buf][row * 64 + swz8(row, kk * 4 + quad) * 8];
            }
            #pragma unroll
            for (int mt = 0; mt < 4; ++mt)
                #pragma unroll
                for (int nt = 0; nt < 2; ++nt)
                    acc[mt][nt] = MFMA_BF16(af[mt], bfr[nt], acc[mt][nt]);
        }
    };

    stage(0, 0);
    __syncthreads();
    int cur = 0;
    for (int kt = 0; kt < 11; ++kt) {
        stage(cur ^ 1, (kt + 1) * 64);
        compute(cur);
        __syncthreads();
        cur ^= 1;
    }
    compute(cur);

    #pragma unroll
    for (int mt = 0; mt < 4; ++mt) {
        #pragma unroll
        for (int nt = 0; nt < 2; ++nt) {
            int gn = n0 + wc + nt * 16 + l15;
            float bv = bias[gn];
            int h = gn >> 6, d = gn & 63;
            #pragma unroll
            for (int r = 0; r < 4; ++r) {
                int gm = m0 + wr + mt * 16 + quad * 4 + r;
                int b = gm >> 8, s = gm & 255;
                out[(((size_t)(b * 12 + h) << 8) + s) * 64 + d] = (bf16)(acc[mt][nt][r] + bv);
            }
        }
    }
}

// ---------------- bf16 GEMM core (output projection epilogue) --------------
__global__ __launch_bounds__(512, 4)
void gemm_out_b(const bf16* __restrict__ X, const bf16* __restrict__ Wb,
                const float* __restrict__ bias, float* __restrict__ out)
{
    __shared__ bf16 As[2][128 * 64];
    __shared__ bf16 Bs[2][128 * 64];

    const int wg  = blockIdx.x;
    const int pos = wg >> 3;
    const int mi  = (wg & 7) * 32 + pos / 6;
    const int ni  = pos % 6;
    const int m0  = mi * 128;
    const int n0  = ni * 128;

    const int tid  = threadIdx.x;
    const int w    = tid >> 6;
    const int lane = tid & 63;
    const int quad = lane >> 4;
    const int l15  = lane & 15;
    const int wr   = (w >> 2) * 64;
    const int wc   = (w & 3) * 32;

    f32x4 acc[4][2] = {};

    auto stage = [&](int buf, int k0) {
        #pragma unroll
        for (int p = 0; p < 2; ++p) {
            int g = p * 512 + tid;
            int row = g >> 3, slot = g & 7;
            int cg  = slot ^ (row & 7);
            gld16(X  + (size_t)(m0 + row) * 768 + k0 + cg * 8, (char*)&As[buf][0] + g * 16);
            gld16(Wb + (size_t)(n0 + row) * 768 + k0 + cg * 8, (char*)&Bs[buf][0] + g * 16);
        }
    };
    auto compute = [&](int buf) {
        #pragma unroll
        for (int kk = 0; kk < 2; ++kk) {
            bf16x8 af[4], bfr[2];
            #pragma unroll
            for (int mt = 0; mt < 4; ++mt) {
                int row = wr + mt * 16 + l15;
                af[mt] = *(const bf16x8*)&As[buf][row * 64 + swz8(row, kk * 4 + quad) * 8];
            }
            #pragma unroll
            for (int nt = 0; nt < 2; ++nt) {
                int row = wc + nt * 16 + l15;
                bfr[nt] = *(const bf16x8*)&Bs[buf][row * 64 + swz8(row, kk * 4 + quad) * 8];
            }
            #pragma unroll
            for (int mt = 0; mt < 4; ++mt)
                #pragma unroll
                for (int nt = 0; nt < 2; ++nt)
                    acc[mt][nt] = MFMA_BF16(af[mt], bfr[nt], acc[mt][nt]);
        }
    };

    stage(0, 0);
    __syncthreads();
    int cur = 0;
    for (int kt = 0; kt < 11; ++kt) {
        stage(cur ^ 1, (kt + 1) * 64);
        compute(cur);
        __syncthreads();
        cur ^= 1;
    }
    compute(cur);

    #pragma unroll
    for (int mt = 0; mt < 4; ++mt) {
        #pragma unroll
        for (int nt = 0; nt < 2; ++nt) {
            int gn = n0 + wc + nt * 16 + l15;
            float bv = bias[gn];
            #pragma unroll
            for (int r = 0; r < 4; ++r) {
                int gm = m0 + wr + mt * 16 + quad * 4 + r;
                out[(size_t)gm * 768 + gn] = acc[mt][nt][r] + bv;
            }
        }
    }
}

// ---------------- V transpose: [B,H,S,DH] -> [B,H,DH,S] -------------------
__global__ __launch_bounds__(256)
void transpose_v(const bf16* __restrict__ vh, bf16* __restrict__ vt)
{
    __shared__ bf16 Ts[64 * 65];
    const int qt = blockIdx.x, h = blockIdx.y, b = blockIdx.z;
    const bf16* src = vh + ((size_t)(b * 12 + h) * 256 + qt * 64) * 64;
    bf16* dst = vt + (size_t)(b * 12 + h) * 64 * 256;

    const int tid = threadIdx.x;
    {
        int row = tid >> 2, c0 = (tid & 3) * 16;
        bf16x8 v0 = *(const bf16x8*)(src + row * 64 + c0);
        bf16x8 v1 = *(const bf16x8*)(src + row * 64 + c0 + 8);
        #pragma unroll
        for (int i = 0; i < 8; ++i) {
            Ts[row * 65 + c0 + i]     = v0[i];
            Ts[row * 65 + c0 + 8 + i] = v1[i];
        }
    }
    __syncthreads();
    {
        int d = tid >> 2, j0 = (tid & 3) * 16;
        bf16x8 o0, o1;
        #pragma unroll
        for (int i = 0; i < 8; ++i) {
            o0[i] = Ts[(j0 + i) * 65 + d];
            o1[i] = Ts[(j0 + 8 + i) * 65 + d];
        }
        *(bf16x8*)(dst + (size_t)d * 256 + qt * 64 + j0)     = o0;
        *(bf16x8*)(dst + (size_t)d * 256 + qt * 64 + j0 + 8) = o1;
    }
}

// ---------------- attention ------------------------------------------------
__global__ __launch_bounds__(256)
void attn_kernel(const bf16* __restrict__ qh, const bf16* __restrict__ kh,
                 const bf16* __restrict__ vt, const bf16* __restrict__ biasb,
                 bf16* __restrict__ ctx)
{
    __shared__ bf16 Qs[64 * 64];        // 8 KB, swizzled
    __shared__ bf16 KVs[2][64 * 64];    // 16 KB: K dbuf during QK^T, V dbuf during PV
    __shared__ bf16 Ps[4 * 16 * 72];    // 9.2 KB per-wave P (LD=72)
    // total 33.2 KB -> 4 blocks/CU

    const int tid  = threadIdx.x;
    const int qt   = blockIdx.x;
    const int h    = blockIdx.y;
    const int b    = blockIdx.z;
    const int w    = tid >> 6;
    const int lane = tid & 63;
    const int quad = lane >> 4;
    const int l15  = lane & 15;

    const size_t bh = (size_t)(b * 12 + h) * 256 * 64;
    const bf16* Qg  = qh + bh + (size_t)qt * 64 * 64;
    const bf16* Kg  = kh + bh;           // [256][64]
    const bf16* Vtg = vt + bh;           // [64][256]

    auto stageT = [&](const bf16* src, size_t rs, bf16* dstLds) {
        #pragma unroll
        for (int p = 0; p < 2; ++p) {
            int g = p * 256 + tid;
            int row = g >> 3, slot = g & 7;
            int cg  = slot ^ (row & 7);
            gld16(src + (size_t)row * rs + cg * 8, (char*)dstLds + g * 16);
        }
    };

    const int browbase = w * 16 + quad * 4;
    const bf16* bb = biasb + h * 4096;
    float bregs[4][4];
    #pragma unroll
    for (int r = 0; r < 4; ++r)
        #pragma unroll
        for (int c4 = 0; c4 < 4; ++c4)
            bregs[r][c4] = (float)bb[(browbase + r) * 64 + c4 * 16 + l15];

    stageT(Qg, 64, Qs);
    stageT(Kg, 64, KVs[0]);
    __syncthreads();

    bf16x8 qf0, qf1;
    {
        int qrow = w * 16 + l15;
        qf0 = *(const bf16x8*)&Qs[qrow * 64 + swz8(qrow, quad) * 8];
        qf1 = *(const bf16x8*)&Qs[qrow * 64 + swz8(qrow, 4 + quad) * 8];
    }

    // ---- QK^T over 4 key chunks, K double-buffered with prefetch ----
    f32x4 sacc[16] = {};
    for (int c = 0; c < 4; ++c) {
        if (c < 3) stageT(Kg + (size_t)(c + 1) * 64 * 64, 64, KVs[(c + 1) & 1]);
        const bf16* Kb = KVs[c & 1];
        #pragma unroll
        for (int jtl = 0; jtl < 4; ++jtl) {
            int krow = jtl * 16 + l15;
            bf16x8 kf0 = *(const bf16x8*)&Kb[krow * 64 + swz8(krow, quad) * 8];
            bf16x8 kf1 = *(const bf16x8*)&Kb[krow * 64 + swz8(krow, 4 + quad) * 8];
            sacc[c * 4 + jtl] = MFMA_BF16(qf0, kf0, sacc[c * 4 + jtl]);
            sacc[c * 4 + jtl] = MFMA_BF16(qf1, kf1, sacc[c * 4 + jtl]);
        }
        __syncthreads();
    }

    stageT(Vtg, 256, KVs[0]);   // V[0] latency hides under softmax

    // ---- softmax (bias from registers) ----
    float p[16][4];
    #pragma unroll
    for (int jt = 0; jt < 16; ++jt)
        #pragma unroll
        for (int r = 0; r < 4; ++r)
            p[jt][r] = sacc[jt][r] * 0.125f + bregs[r][jt & 3];
    float invl[4];
    #pragma unroll
    for (int r = 0; r < 4; ++r) {
        float m = p[0][r];
        #pragma unroll
        for (int jt = 1; jt < 16; ++jt) m = fmaxf(m, p[jt][r]);
        #pragma unroll
        for (int off = 1; off < 16; off <<= 1)
            m = fmaxf(m, __shfl_xor(m, off, 64));
        float s = 0.f;
        #pragma unroll
        for (int jt = 0; jt < 16; ++jt) {
            p[jt][r] = __expf(p[jt][r] - m);
            s += p[jt][r];
        }
        #pragma unroll
        for (int off = 1; off < 16; off <<= 1)
            s += __shfl_xor(s, off, 64);
        invl[r] = 1.0f / s;
    }

    // ---- PV over 4 key chunks, V double-buffered with prefetch ----
    f32x4 cacc[4] = {};
    bf16* Pw = &Ps[w * 16 * 72];
    for (int c = 0; c < 4; ++c) {
        #pragma unroll
        for (int jtl = 0; jtl < 4; ++jtl) {
            int jt = c * 4 + jtl;
            #pragma unroll
            for (int r = 0; r < 4; ++r)
                Pw[(quad * 4 + r) * 72 + jtl * 16 + l15] = (bf16)(p[jt][r] * invl[r]);
        }
        __syncthreads();
        if (c < 3) stageT(Vtg + (size_t)(c + 1) * 64, 256, KVs[(c + 1) & 1]);
        const bf16* Vb = KVs[c & 1];
        bf16x8 pf0 = *(const bf16x8*)&Pw[l15 * 72 + quad * 8];
        bf16x8 pf1 = *(const bf16x8*)&Pw[l15 * 72 + 32 + quad * 8];
        #pragma unroll
        for (int dt = 0; dt < 4; ++dt) {
            int vrow = dt * 16 + l15;
            bf16x8 vf0 = *(const bf16x8*)&Vb[vrow * 64 + swz8(vrow, quad) * 8];
            bf16x8 vf1 = *(const bf16x8*)&Vb[vrow * 64 + swz8(vrow, 4 + quad) * 8];
            cacc[dt] = MFMA_BF16(pf0, vf0, cacc[dt]);
            cacc[dt] = MFMA_BF16(pf1, vf1, cacc[dt]);
        }
    }

    const size_t obase = ((size_t)b * 256) * 768 + (size_t)h * 64;
    #pragma unroll
    for (int dt = 0; dt < 4; ++dt) {
        #pragma unroll
        for (int r = 0; r < 4; ++r) {
            int s = qt * 64 + w * 16 + quad * 4 + r;
            int d = dt * 16 + l15;
            ctx[obase + (size_t)s * 768 + d] = (bf16)cacc[dt][r];
        }
    }
}

extern "C" void kernel_launch(void* const* d_in, const int* in_sizes, int n_in,
                              void* d_out, int out_size, void* d_ws, size_t ws_size,
                              hipStream_t stream) {
    (void)in_sizes; (void)n_in; (void)out_size; (void)ws_size;
    const float* q     = (const float*)d_in[0];
    const float* k     = (const float*)d_in[1];
    const float* v     = (const float*)d_in[2];
    const float* Wq    = (const float*)d_in[3];
    const float* bq    = (const float*)d_in[4];
    const float* Wk    = (const float*)d_in[5];
    const float* bk    = (const float*)d_in[6];
    const float* Wv    = (const float*)d_in[7];
    const float* bv    = (const float*)d_in[8];
    const float* Wo    = (const float*)d_in[9];
    const float* bo    = (const float*)d_in[10];
    const float* table = (const float*)d_in[11];

    const size_t NE = (size_t)128 * 256 * 768;
    const size_t WE = (size_t)768 * 768;

    bf16* qh  = (bf16*)d_ws;
    bf16* kh  = qh + NE;
    bf16* vh  = kh + NE;
    bf16* vt  = vh + NE;
    bf16* ctx = vh;
    float* out = (float*)d_out;

    bf16* xq_b  = (bf16*)d_out;
    bf16* xk_b  = xq_b + NE;
    bf16* xv_b  = xq_b;                  // reuse after q-GEMM done
    bf16* biasb = xk_b;                  // valid after k-GEMM done
    bf16* wq_b  = vt;
    bf16* wk_b  = wq_b + WE;
    bf16* wv_b  = wk_b + WE;
    bf16* wo_b  = qh;                    // valid after attn completes

    const int XG = (int)(NE / 8);
    const int WG = (int)(WE / 8);

    dim3 blk(256);
    dim3 blk512(512);
    cvt_f32_bf16<<<2048, blk, 0, stream>>>(q,  xq_b, XG);
    cvt_f32_bf16<<<2048, blk, 0, stream>>>(k,  xk_b, XG);
    cvt_f32_bf16<<<288,  blk, 0, stream>>>(Wq, wq_b, WG);
    cvt_f32_bf16<<<288,  blk, 0, stream>>>(Wk, wk_b, WG);
    cvt_f32_bf16<<<288,  blk, 0, stream>>>(Wv, wv_b, WG);

    gemm_qkv_b<<<1536, blk512, 0, stream>>>(xq_b, wq_b, bq, qh);
    gemm_qkv_b<<<1536, blk512, 0, stream>>>(xk_b, wk_b, bk, kh);
    bias_expand<<<12, blk, 0, stream>>>(table, biasb);       // xk_b dead now
    cvt_f32_bf16<<<2048, blk, 0, stream>>>(v, xv_b, XG);     // xq_b dead now
    gemm_qkv_b<<<1536, blk512, 0, stream>>>(xv_b, wv_b, bv, vh);

    transpose_v<<<dim3(4, 12, 128), blk, 0, stream>>>(vh, vt);   // kills w*_b
    attn_kernel<<<dim3(4, 12, 128), blk, 0, stream>>>(qh, kh, vt, biasb, ctx);

    cvt_f32_bf16<<<288, blk, 0, stream>>>(Wo, wo_b, WG);     // qh dead now
    gemm_out_b<<<1536, blk512, 0, stream>>>(ctx, wo_b, bo, out);
}